// Round 3
// baseline (1912.999 us; speedup 1.0000x reference)
//
#include <hip/hip_runtime.h>

#define B_ROWS 32768
#define KCODES 4096
#define DLAT 128

// ---------------------------------------------------------------------------
// f32 GEMM, C = A[MxK] @ B[KxN] + bias[N]. 128x128 tile, BK=16, 256 threads,
// 8x8 micro-tile split 4+4 at distance 64 (bank-conflict-light reads).
// Double-buffered LDS with async-stage split (issue loads early, LDS-write
// after compute) to hide global latency. As/Bs-transpose padded to 132.
// M,N must be multiples of 128. KTAIL=true handles K % 16 != 0.
// ---------------------------------------------------------------------------
template<bool KTAIL>
__global__ __launch_bounds__(256)
void sgemm_f32(const float* __restrict__ A, const float* __restrict__ Bm,
               const float* __restrict__ bias, float* __restrict__ C,
               int M, int N, int K)
{
  __shared__ float As[2][16][132];
  __shared__ float Bs[2][16][128];
  const int tid = threadIdx.x;
  const int tr = tid >> 4;   // 0..15
  const int tc = tid & 15;   // 0..15
  const int m0 = blockIdx.y * 128;
  const int n0 = blockIdx.x * 128;

  const int arow = tid >> 2;          // 0..63
  const int acol = (tid & 3) << 2;    // 0,4,8,12
  const int brow = tid >> 5;          // 0..7
  const int bcol = (tid & 31) << 2;   // 0..124

  float acc[8][8];
  #pragma unroll
  for (int i = 0; i < 8; ++i)
    #pragma unroll
    for (int j = 0; j < 8; ++j) acc[i][j] = 0.f;

  const int nk = (K + 15) >> 4;
  float4 pa0, pa1, pb0, pb1;

  auto gload = [&](int k0) {
    const float* s0 = A + (size_t)(m0 + arow) * K + (k0 + acol);
    const float* s1 = A + (size_t)(m0 + arow + 64) * K + (k0 + acol);
    if (!KTAIL || (k0 + acol + 3 < K)) {
      pa0 = *reinterpret_cast<const float4*>(s0);
      pa1 = *reinterpret_cast<const float4*>(s1);
    } else {
      pa0.x = (k0+acol+0 < K) ? s0[0] : 0.f;  pa1.x = (k0+acol+0 < K) ? s1[0] : 0.f;
      pa0.y = (k0+acol+1 < K) ? s0[1] : 0.f;  pa1.y = (k0+acol+1 < K) ? s1[1] : 0.f;
      pa0.z = (k0+acol+2 < K) ? s0[2] : 0.f;  pa1.z = (k0+acol+2 < K) ? s1[2] : 0.f;
      pa0.w = (k0+acol+3 < K) ? s0[3] : 0.f;  pa1.w = (k0+acol+3 < K) ? s1[3] : 0.f;
    }
    const int r0 = k0 + brow, r1 = k0 + brow + 8;
    pb0 = (!KTAIL || r0 < K) ? *reinterpret_cast<const float4*>(Bm + (size_t)r0 * N + n0 + bcol)
                             : make_float4(0.f, 0.f, 0.f, 0.f);
    pb1 = (!KTAIL || r1 < K) ? *reinterpret_cast<const float4*>(Bm + (size_t)r1 * N + n0 + bcol)
                             : make_float4(0.f, 0.f, 0.f, 0.f);
  };
  auto lstore = [&](int buf) {
    As[buf][acol+0][arow]    = pa0.x; As[buf][acol+1][arow]    = pa0.y;
    As[buf][acol+2][arow]    = pa0.z; As[buf][acol+3][arow]    = pa0.w;
    As[buf][acol+0][arow+64] = pa1.x; As[buf][acol+1][arow+64] = pa1.y;
    As[buf][acol+2][arow+64] = pa1.z; As[buf][acol+3][arow+64] = pa1.w;
    *reinterpret_cast<float4*>(&Bs[buf][brow][bcol])     = pb0;
    *reinterpret_cast<float4*>(&Bs[buf][brow + 8][bcol]) = pb1;
  };

  gload(0);
  lstore(0);
  __syncthreads();

  #pragma unroll 1
  for (int kt = 0; kt < nk; ++kt) {
    const int cur = kt & 1;
    const bool pf = (kt + 1 < nk);
    if (pf) gload((kt + 1) << 4);          // issue early: latency hides under FMAs
    #pragma unroll
    for (int kk = 0; kk < 16; ++kk) {
      float a[8], b[8];
      float4 t;
      t = *reinterpret_cast<const float4*>(&As[cur][kk][tr * 4]);      a[0]=t.x;a[1]=t.y;a[2]=t.z;a[3]=t.w;
      t = *reinterpret_cast<const float4*>(&As[cur][kk][64 + tr * 4]); a[4]=t.x;a[5]=t.y;a[6]=t.z;a[7]=t.w;
      t = *reinterpret_cast<const float4*>(&Bs[cur][kk][tc * 4]);      b[0]=t.x;b[1]=t.y;b[2]=t.z;b[3]=t.w;
      t = *reinterpret_cast<const float4*>(&Bs[cur][kk][64 + tc * 4]); b[4]=t.x;b[5]=t.y;b[6]=t.z;b[7]=t.w;
      #pragma unroll
      for (int i = 0; i < 8; ++i)
        #pragma unroll
        for (int j = 0; j < 8; ++j)
          acc[i][j] = fmaf(a[i], b[j], acc[i][j]);
    }
    if (pf) lstore(cur ^ 1);               // write-late: vmcnt mostly drained
    __syncthreads();
  }

  // epilogue: rows m0 + ih*64 + tr*4 + i, cols n0 + jh*64 + tc*4 + j
  #pragma unroll
  for (int ih = 0; ih < 2; ++ih)
    #pragma unroll
    for (int i = 0; i < 4; ++i) {
      const int m = m0 + ih * 64 + tr * 4 + i;
      #pragma unroll
      for (int jh = 0; jh < 2; ++jh) {
        const int c0 = n0 + jh * 64 + tc * 4;
        float4 o;
        o.x = acc[ih*4+i][jh*4+0] + bias[c0+0];
        o.y = acc[ih*4+i][jh*4+1] + bias[c0+1];
        o.z = acc[ih*4+i][jh*4+2] + bias[c0+2];
        o.w = acc[ih*4+i][jh*4+3] + bias[c0+3];
        *reinterpret_cast<float4*>(C + (size_t)m * N + c0) = o;
      }
    }
}

// ---------------------------------------------------------------------------
// Row-wise LayerNorm (+affine) + exact GELU (erf). One block (256 thr) per row.
// ---------------------------------------------------------------------------
__global__ __launch_bounds__(256)
void ln_gelu_kernel(const float* __restrict__ in, float* __restrict__ out,
                    const float* __restrict__ g, const float* __restrict__ be, int Wd)
{
  __shared__ float rs[4], rs2[4];
  const int row = blockIdx.x;
  const float* x = in + (size_t)row * Wd;
  float s = 0.f, s2 = 0.f;
  for (int c = threadIdx.x; c < Wd; c += 256) { float v = x[c]; s += v; s2 += v * v; }
  #pragma unroll
  for (int m = 32; m; m >>= 1) { s += __shfl_down(s, m); s2 += __shfl_down(s2, m); }
  const int lane = threadIdx.x & 63, wid = threadIdx.x >> 6;
  if (lane == 0) { rs[wid] = s; rs2[wid] = s2; }
  __syncthreads();
  if (threadIdx.x == 0) {
    float S = rs[0] + rs[1] + rs[2] + rs[3];
    float S2 = rs2[0] + rs2[1] + rs2[2] + rs2[3];
    float mean = S / Wd;
    float var = S2 / Wd - mean * mean;
    rs[0] = mean; rs2[0] = 1.0f / sqrtf(var + 1e-5f);
  }
  __syncthreads();
  const float mean = rs[0], inv = rs2[0];
  for (int c = threadIdx.x; c < Wd; c += 256) {
    float v = (x[c] - mean) * inv * g[c] + be[c];
    out[(size_t)row * Wd + c] = 0.5f * v * (1.f + erff(v * 0.70710678118654752f));
  }
}

// ---------------------------------------------------------------------------
// VQ streaming argmin. Block = 128 rows x 1024-code split (grid 4 x 256).
// Flattened 64 k-tiles (8 chunks x 8 k-steps), double-buffered like sgemm.
// Running per-row (best,idx) folded after each 128-code chunk.
// score = ||e||^2 - 2 z.e ; tie-break = lowest index (ascending scan, strict <).
// ---------------------------------------------------------------------------
__global__ __launch_bounds__(256)
void vq_argmin(const float* __restrict__ Z, const float* __restrict__ E,
               const float* __restrict__ e2, float* __restrict__ pval,
               int* __restrict__ pidx)
{
  __shared__ float As[2][16][132];
  __shared__ float Bs[2][16][132];
  const int tid = threadIdx.x;
  const int tr = tid >> 4, tc = tid & 15;
  const int m0 = blockIdx.y * 128;
  const int split = blockIdx.x;            // 0..3, 1024 codes each

  const int arow = tid >> 2;
  const int acol = (tid & 3) << 2;

  float bv[8];
  int   bi[8];
  #pragma unroll
  for (int i = 0; i < 8; ++i) { bv[i] = 3.4e38f; bi[i] = 0x7fffffff; }

  float4 pa0, pa1, pb0, pb1;

  auto gload = [&](int t) {                 // t = ch*8 + kt, 0..63
    const int k0 = (t & 7) << 4;
    const int n0 = split * 1024 + (t >> 3) * 128;
    pa0 = *reinterpret_cast<const float4*>(Z + (size_t)(m0 + arow) * 128 + k0 + acol);
    pa1 = *reinterpret_cast<const float4*>(Z + (size_t)(m0 + arow + 64) * 128 + k0 + acol);
    pb0 = *reinterpret_cast<const float4*>(E + (size_t)(n0 + arow) * 128 + k0 + acol);
    pb1 = *reinterpret_cast<const float4*>(E + (size_t)(n0 + arow + 64) * 128 + k0 + acol);
  };
  auto lstore = [&](int buf) {
    As[buf][acol+0][arow]    = pa0.x; As[buf][acol+1][arow]    = pa0.y;
    As[buf][acol+2][arow]    = pa0.z; As[buf][acol+3][arow]    = pa0.w;
    As[buf][acol+0][arow+64] = pa1.x; As[buf][acol+1][arow+64] = pa1.y;
    As[buf][acol+2][arow+64] = pa1.z; As[buf][acol+3][arow+64] = pa1.w;
    Bs[buf][acol+0][arow]    = pb0.x; Bs[buf][acol+1][arow]    = pb0.y;
    Bs[buf][acol+2][arow]    = pb0.z; Bs[buf][acol+3][arow]    = pb0.w;
    Bs[buf][acol+0][arow+64] = pb1.x; Bs[buf][acol+1][arow+64] = pb1.y;
    Bs[buf][acol+2][arow+64] = pb1.z; Bs[buf][acol+3][arow+64] = pb1.w;
  };

  gload(0);
  lstore(0);
  __syncthreads();

  #pragma unroll 1
  for (int ch = 0; ch < 8; ++ch) {
    float acc[8][8];
    #pragma unroll
    for (int i = 0; i < 8; ++i)
      #pragma unroll
      for (int j = 0; j < 8; ++j) acc[i][j] = 0.f;

    #pragma unroll 1
    for (int kt = 0; kt < 8; ++kt) {
      const int t = ch * 8 + kt;
      const int cur = t & 1;
      const bool pf = (t + 1 < 64);
      if (pf) gload(t + 1);
      #pragma unroll
      for (int kk = 0; kk < 16; ++kk) {
        float a[8], b[8];
        float4 v;
        v = *reinterpret_cast<const float4*>(&As[cur][kk][tr * 4]);      a[0]=v.x;a[1]=v.y;a[2]=v.z;a[3]=v.w;
        v = *reinterpret_cast<const float4*>(&As[cur][kk][64 + tr * 4]); a[4]=v.x;a[5]=v.y;a[6]=v.z;a[7]=v.w;
        v = *reinterpret_cast<const float4*>(&Bs[cur][kk][tc * 4]);      b[0]=v.x;b[1]=v.y;b[2]=v.z;b[3]=v.w;
        v = *reinterpret_cast<const float4*>(&Bs[cur][kk][64 + tc * 4]); b[4]=v.x;b[5]=v.y;b[6]=v.z;b[7]=v.w;
        #pragma unroll
        for (int i = 0; i < 8; ++i)
          #pragma unroll
          for (int j = 0; j < 8; ++j)
            acc[i][j] = fmaf(a[i], b[j], acc[i][j]);
      }
      if (pf) lstore(cur ^ 1);
      __syncthreads();
    }

    // fold this chunk (codes nb .. nb+127) into running argmin, ascending order
    const int nb = split * 1024 + ch * 128;
    const float4 e20 = *reinterpret_cast<const float4*>(e2 + nb + tc * 4);
    const float4 e21 = *reinterpret_cast<const float4*>(e2 + nb + 64 + tc * 4);
    const float ev[8] = { e20.x, e20.y, e20.z, e20.w, e21.x, e21.y, e21.z, e21.w };
    #pragma unroll
    for (int i = 0; i < 8; ++i) {
      #pragma unroll
      for (int jh = 0; jh < 2; ++jh)
        #pragma unroll
        for (int j = 0; j < 4; ++j) {
          const int code = nb + jh * 64 + tc * 4 + j;
          const float sc = ev[jh * 4 + j] - 2.f * acc[i][jh * 4 + j];
          if (sc < bv[i]) { bv[i] = sc; bi[i] = code; }
        }
    }
  }

  // cross-lane reduce over the 16 tc threads per row
  #pragma unroll
  for (int i = 0; i < 8; ++i) {
    float v = bv[i]; int ix = bi[i];
    #pragma unroll
    for (int m = 1; m < 16; m <<= 1) {
      float ov = __shfl_xor(v, m);
      int oi = __shfl_xor(ix, m);
      if (ov < v || (ov == v && oi < ix)) { v = ov; ix = oi; }
    }
    if (tc == 0) {
      const int row = m0 + (i >> 2) * 64 + tr * 4 + (i & 3);
      pval[(size_t)row * 4 + split] = v;
      pidx[(size_t)row * 4 + split] = ix;
    }
  }
}

// final argmin across 4 code-splits; histogram; index outputs
__global__ void vq_reduce(const float* __restrict__ pval, const int* __restrict__ pidx,
                          int* __restrict__ idxout, float* __restrict__ idxf,
                          int* __restrict__ counts)
{
  const int b = blockIdx.x * 256 + threadIdx.x;
  if (b >= B_ROWS) return;
  float best = 3.4e38f; int bi = 0;
  #pragma unroll
  for (int j = 0; j < 4; ++j) {            // ascending split -> lowest idx on tie
    float v = pval[(size_t)b * 4 + j];
    if (v < best) { best = v; bi = pidx[(size_t)b * 4 + j]; }
  }
  idxout[b] = bi;
  idxf[b] = (float)bi;
  atomicAdd(&counts[bi], 1);
}

// gather z_q -> z_q_st output; deterministic per-block commitment partial sums
__global__ __launch_bounds__(256)
void gather_commit(const int* __restrict__ idx, const float* __restrict__ E,
                   const float* __restrict__ ZE, float* __restrict__ ZQ,
                   float* __restrict__ cpart)
{
  __shared__ float red[4];
  const int b = blockIdx.x * 8 + (threadIdx.x >> 5);
  const int ch = threadIdx.x & 31;
  const int k = idx[b];
  float4 q = *reinterpret_cast<const float4*>(E + (size_t)k * 128 + ch * 4);
  float4 z = *reinterpret_cast<const float4*>(ZE + (size_t)b * 128 + ch * 4);
  *reinterpret_cast<float4*>(ZQ + (size_t)b * 128 + ch * 4) = q;
  float dx = q.x - z.x, dy = q.y - z.y, dz = q.z - z.z, dw = q.w - z.w;
  float s = dx * dx + dy * dy + dz * dz + dw * dw;
  #pragma unroll
  for (int m = 32; m; m >>= 1) s += __shfl_down(s, m);
  const int lane = threadIdx.x & 63, wid = threadIdx.x >> 6;
  if (lane == 0) red[wid] = s;
  __syncthreads();
  if (threadIdx.x == 0) cpart[blockIdx.x] = red[0] + red[1] + red[2] + red[3];
}

__global__ void e2_kernel(const float* __restrict__ E, float* __restrict__ e2)
{
  const int k = blockIdx.x * 256 + threadIdx.x;
  if (k >= KCODES) return;
  float s = 0.f;
  #pragma unroll 4
  for (int d = 0; d < 128; ++d) { float v = E[(size_t)k * 128 + d]; s += v * v; }
  e2[k] = s;
}

__global__ void zero_counts(int* counts)
{
  const int i = blockIdx.x * 256 + threadIdx.x;
  if (i < KCODES) counts[i] = 0;
}

__global__ void gelu_ew(float* __restrict__ p, int n)
{
  const int i = blockIdx.x * 256 + threadIdx.x;
  if (i < n) { float v = p[i]; p[i] = 0.5f * v * (1.f + erff(v * 0.70710678118654752f)); }
}

// tiny GEMM: V[Mx2] = T[Mx128] @ W6[128x2] + b6
__global__ void gemm_n2(const float* __restrict__ T, const float* __restrict__ W6,
                        const float* __restrict__ b6, float* __restrict__ V, int M)
{
  const int r = blockIdx.x * 256 + threadIdx.x;
  if (r >= M) return;
  float a0 = b6[0], a1 = b6[1];
  #pragma unroll 4
  for (int d = 0; d < 128; ++d) {
    float t = T[(size_t)r * 128 + d];
    a0 = fmaf(t, W6[d * 2 + 0], a0);
    a1 = fmaf(t, W6[d * 2 + 1], a1);
  }
  V[r * 2 + 0] = a0; V[r * 2 + 1] = a1;
}

__global__ void vel_gather(const int* __restrict__ idx, const float* __restrict__ V,
                           float* __restrict__ out)
{
  const int b = blockIdx.x * 256 + threadIdx.x;
  if (b >= B_ROWS) return;
  const int k = idx[b];
  out[b * 2 + 0] = V[k * 2 + 0];
  out[b * 2 + 1] = V[k * 2 + 1];
}

// deterministic scalar finish: commitment, perplexity, n_active
__global__ __launch_bounds__(256)
void stats_kernel(const float* __restrict__ cpart, const int* __restrict__ counts,
                  float* __restrict__ outs)
{
  __shared__ float sh[256];
  __shared__ float sh2[256];
  __shared__ int shi[256];
  const int t = threadIdx.x;
  float cs = 0.f;
  for (int i = t; i < 4096; i += 256) cs += cpart[i];
  float h = 0.f; int act = 0;
  for (int k = t; k < KCODES; k += 256) {
    float avg = counts[k] * (1.0f / 32768.0f);
    h += avg * logf(avg + 1e-10f);
    act += (avg > 0.001f) ? 1 : 0;
  }
  sh[t] = cs; sh2[t] = h; shi[t] = act;
  __syncthreads();
  for (int s = 128; s; s >>= 1) {
    if (t < s) { sh[t] += sh[t + s]; sh2[t] += sh2[t + s]; shi[t] += shi[t + s]; }
    __syncthreads();
  }
  if (t == 0) {
    outs[0] = 0.25f * sh[0] / (32768.0f * 128.0f);  // commitment
    outs[1] = expf(-sh2[0]);                        // perplexity
    outs[2] = (float)shi[0];                        // n_active
  }
}

extern "C" void kernel_launch(void* const* d_in, const int* in_sizes, int n_in,
                              void* d_out, int out_size, void* d_ws, size_t ws_size,
                              hipStream_t stream)
{
  const float* x   = (const float*)d_in[0];
  const float* W1  = (const float*)d_in[1];
  const float* b1  = (const float*)d_in[2];
  const float* g1  = (const float*)d_in[3];
  const float* be1 = (const float*)d_in[4];
  const float* W2  = (const float*)d_in[5];
  const float* b2  = (const float*)d_in[6];
  const float* g2  = (const float*)d_in[7];
  const float* be2 = (const float*)d_in[8];
  const float* W3  = (const float*)d_in[9];
  const float* b3  = (const float*)d_in[10];
  const float* emb = (const float*)d_in[11];
  const float* W4  = (const float*)d_in[12];
  const float* b4  = (const float*)d_in[13];
  const float* g3  = (const float*)d_in[14];
  const float* be3 = (const float*)d_in[15];
  const float* W5  = (const float*)d_in[16];
  const float* b5  = (const float*)d_in[17];
  const float* W6  = (const float*)d_in[18];
  const float* b6  = (const float*)d_in[19];

  float* out = (float*)d_out;
  float* o_vel  = out;                                   // [B,2]
  float* o_ze   = out + 65536;                           // [B,128]
  float* o_zq   = out + 65536 + B_ROWS * 128;            // [B,128]
  float* o_idx  = out + 65536 + 2 * B_ROWS * 128;        // [B] (as float)
  float* o_scal = o_idx + B_ROWS;                        // 3 scalars

  float* ws = (float*)d_ws;
  float* h1    = ws;                        // [B,512]  (dead after GEMM2)
  float* pval  = ws;                        // [B,4]    (live: VQ only)
  int*   pidx  = (int*)(ws + 1048576);      // [B,4]
  float* t1    = ws + 2097152;              // [4096,256]
  float* t2    = ws + 3145728;              // [4096,128]
  float* vv    = ws + 3670016;              // [4096,2]
  float* h2    = ws + 16777216;             // [B,256]
  float* e2    = ws + 25165824;             // [4096]
  int*   ind   = (int*)(ws + 25169920);     // [B]
  int*   cnt   = (int*)(ws + 25202688);     // [4096]
  float* cpart = ws + 25206784;             // [4096]

  // 1. init
  zero_counts<<<16, 256, 0, stream>>>(cnt);
  e2_kernel<<<16, 256, 0, stream>>>(emb, e2);

  // 2. encoder
  sgemm_f32<true><<<dim3(4, 256), 256, 0, stream>>>(x, W1, b1, h1, B_ROWS, 512, 1420);
  ln_gelu_kernel<<<B_ROWS, 256, 0, stream>>>(h1, h1, g1, be1, 512);
  sgemm_f32<false><<<dim3(2, 256), 256, 0, stream>>>(h1, W2, b2, h2, B_ROWS, 256, 512);
  ln_gelu_kernel<<<B_ROWS, 256, 0, stream>>>(h2, h2, g2, be2, 256);
  sgemm_f32<false><<<dim3(1, 256), 256, 0, stream>>>(h2, W3, b3, o_ze, B_ROWS, 128, 256);

  // 3. VQ: streaming argmin + reduce + gather + commitment partials + histogram
  vq_argmin<<<dim3(4, 256), 256, 0, stream>>>(o_ze, emb, e2, pval, pidx);
  vq_reduce<<<128, 256, 0, stream>>>(pval, pidx, ind, o_idx, cnt);
  gather_commit<<<4096, 256, 0, stream>>>(ind, emb, o_ze, o_zq, cpart);

  // 4. decoder on the 4096 distinct codes, then gather
  sgemm_f32<false><<<dim3(2, 32), 256, 0, stream>>>(emb, W4, b4, t1, KCODES, 256, 128);
  ln_gelu_kernel<<<KCODES, 256, 0, stream>>>(t1, t1, g3, be3, 256);
  sgemm_f32<false><<<dim3(1, 32), 256, 0, stream>>>(t1, W5, b5, t2, KCODES, 128, 256);
  gelu_ew<<<(KCODES * 128 + 255) / 256, 256, 0, stream>>>(t2, KCODES * 128);
  gemm_n2<<<(KCODES + 255) / 256, 256, 0, stream>>>(t2, W6, b6, vv, KCODES);
  vel_gather<<<128, 256, 0, stream>>>(ind, vv, o_vel);

  // 5. scalars
  stats_kernel<<<1, 256, 0, stream>>>(cpart, cnt, o_scal);
}

// Round 4
// 1546.878 us; speedup vs baseline: 1.2367x; 1.2367x over previous
//
#include <hip/hip_runtime.h>

#define B_ROWS 32768
#define KCODES 4096
#define DLAT 128

// ---------------------------------------------------------------------------
// f32 GEMM, C = A[MxK] @ B[KxN] + bias[N]. 128x128 tile, BK=16, 256 threads.
// Single-buffered LDS (round-2 structure: 68 VGPR, ~26% occupancy — the
// double-buffered variant hit 188 VGPR / 11.8% occupancy and was SLOWER).
// Bank-conflict-light reads: 8x8 micro-tile split 4+4 at distance 64
// (broadcast + 2-way only); As transposed tile padded to stride 132
// (write conflicts 4-way -> 2-way). M,N multiples of 128; KTAIL for K%16!=0.
// ---------------------------------------------------------------------------
template<bool KTAIL>
__global__ __launch_bounds__(256)
void sgemm_f32(const float* __restrict__ A, const float* __restrict__ Bm,
               const float* __restrict__ bias, float* __restrict__ C,
               int M, int N, int K)
{
  __shared__ float As[16][132];
  __shared__ float Bs[16][128];
  const int tid = threadIdx.x;
  const int tr = tid >> 4;   // 0..15
  const int tc = tid & 15;   // 0..15
  const int m0 = blockIdx.y * 128;
  const int n0 = blockIdx.x * 128;

  float acc[8][8];
  #pragma unroll
  for (int i = 0; i < 8; ++i)
    #pragma unroll
    for (int j = 0; j < 8; ++j) acc[i][j] = 0.f;

  const int arow = tid >> 2;          // 0..63 (two passes, +64)
  const int acol = (tid & 3) << 2;    // 0,4,8,12
  const int brow = tid >> 5;          // 0..7 (two passes, +8)
  const int bcol = (tid & 31) << 2;   // 0..124

  const int nk = (K + 15) >> 4;
  #pragma unroll 1
  for (int kt = 0; kt < nk; ++kt) {
    const int k0 = kt << 4;
    // stage A tile (128 rows x 16 k), transposed into As[k][m], stride 132
    #pragma unroll
    for (int p = 0; p < 2; ++p) {
      const int r = arow + p * 64;
      const float* src = A + (size_t)(m0 + r) * K + (k0 + acol);
      float4 v;
      if (!KTAIL || (k0 + acol + 3 < K)) {
        v = *reinterpret_cast<const float4*>(src);
      } else {
        v.x = (k0 + acol + 0 < K) ? src[0] : 0.f;
        v.y = (k0 + acol + 1 < K) ? src[1] : 0.f;
        v.z = (k0 + acol + 2 < K) ? src[2] : 0.f;
        v.w = (k0 + acol + 3 < K) ? src[3] : 0.f;
      }
      As[acol + 0][r] = v.x; As[acol + 1][r] = v.y;
      As[acol + 2][r] = v.z; As[acol + 3][r] = v.w;
    }
    // stage B tile (16 k x 128 n), natural layout
    #pragma unroll
    for (int p = 0; p < 2; ++p) {
      const int r = brow + p * 8;
      float4 v = make_float4(0.f, 0.f, 0.f, 0.f);
      if (!KTAIL || (k0 + r < K))
        v = *reinterpret_cast<const float4*>(Bm + (size_t)(k0 + r) * N + (n0 + bcol));
      *reinterpret_cast<float4*>(&Bs[r][bcol]) = v;
    }
    __syncthreads();
    #pragma unroll
    for (int kk = 0; kk < 16; ++kk) {
      float a[8], b[8];
      float4 t;
      t = *reinterpret_cast<const float4*>(&As[kk][tr * 4]);      a[0]=t.x;a[1]=t.y;a[2]=t.z;a[3]=t.w;
      t = *reinterpret_cast<const float4*>(&As[kk][64 + tr * 4]); a[4]=t.x;a[5]=t.y;a[6]=t.z;a[7]=t.w;
      t = *reinterpret_cast<const float4*>(&Bs[kk][tc * 4]);      b[0]=t.x;b[1]=t.y;b[2]=t.z;b[3]=t.w;
      t = *reinterpret_cast<const float4*>(&Bs[kk][64 + tc * 4]); b[4]=t.x;b[5]=t.y;b[6]=t.z;b[7]=t.w;
      #pragma unroll
      for (int i = 0; i < 8; ++i)
        #pragma unroll
        for (int j = 0; j < 8; ++j)
          acc[i][j] = fmaf(a[i], b[j], acc[i][j]);
    }
    __syncthreads();
  }

  // epilogue: rows m0 + ih*64 + tr*4 + i, cols n0 + jh*64 + tc*4 + j
  #pragma unroll
  for (int ih = 0; ih < 2; ++ih)
    #pragma unroll
    for (int i = 0; i < 4; ++i) {
      const int m = m0 + ih * 64 + tr * 4 + i;
      #pragma unroll
      for (int jh = 0; jh < 2; ++jh) {
        const int c0 = n0 + jh * 64 + tc * 4;
        float4 o;
        o.x = acc[ih*4+i][jh*4+0] + bias[c0+0];
        o.y = acc[ih*4+i][jh*4+1] + bias[c0+1];
        o.z = acc[ih*4+i][jh*4+2] + bias[c0+2];
        o.w = acc[ih*4+i][jh*4+3] + bias[c0+3];
        *reinterpret_cast<float4*>(C + (size_t)m * N + c0) = o;
      }
    }
}

// ---------------------------------------------------------------------------
// Row-wise LayerNorm (+affine) + exact GELU (erf). One block (256 thr) per row.
// ---------------------------------------------------------------------------
__global__ __launch_bounds__(256)
void ln_gelu_kernel(const float* __restrict__ in, float* __restrict__ out,
                    const float* __restrict__ g, const float* __restrict__ be, int Wd)
{
  __shared__ float rs[4], rs2[4];
  const int row = blockIdx.x;
  const float* x = in + (size_t)row * Wd;
  float s = 0.f, s2 = 0.f;
  for (int c = threadIdx.x; c < Wd; c += 256) { float v = x[c]; s += v; s2 += v * v; }
  #pragma unroll
  for (int m = 32; m; m >>= 1) { s += __shfl_down(s, m); s2 += __shfl_down(s2, m); }
  const int lane = threadIdx.x & 63, wid = threadIdx.x >> 6;
  if (lane == 0) { rs[wid] = s; rs2[wid] = s2; }
  __syncthreads();
  if (threadIdx.x == 0) {
    float S = rs[0] + rs[1] + rs[2] + rs[3];
    float S2 = rs2[0] + rs2[1] + rs2[2] + rs2[3];
    float mean = S / Wd;
    float var = S2 / Wd - mean * mean;
    rs[0] = mean; rs2[0] = 1.0f / sqrtf(var + 1e-5f);
  }
  __syncthreads();
  const float mean = rs[0], inv = rs2[0];
  for (int c = threadIdx.x; c < Wd; c += 256) {
    float v = (x[c] - mean) * inv * g[c] + be[c];
    out[(size_t)row * Wd + c] = 0.5f * v * (1.f + erff(v * 0.70710678118654752f));
  }
}

// ---------------------------------------------------------------------------
// VQ streaming argmin. Block = 128 rows x 1024-code split (grid 4 x 256).
// Single-buffered (round-2 structure), padded tiles, 4+4 split reads.
// Running per-row (best,idx) folded after each 128-code chunk.
// score = ||e||^2 - 2 z.e ; tie-break = lowest index (ascending scan, strict <).
// ---------------------------------------------------------------------------
__global__ __launch_bounds__(256)
void vq_argmin(const float* __restrict__ Z, const float* __restrict__ E,
               const float* __restrict__ e2, float* __restrict__ pval,
               int* __restrict__ pidx)
{
  __shared__ float As[16][132];
  __shared__ float Bs[16][132];
  const int tid = threadIdx.x;
  const int tr = tid >> 4, tc = tid & 15;
  const int m0 = blockIdx.y * 128;
  const int split = blockIdx.x;            // 0..3, 1024 codes each

  const int arow = tid >> 2;
  const int acol = (tid & 3) << 2;

  float bv[8];
  int   bi[8];
  #pragma unroll
  for (int i = 0; i < 8; ++i) { bv[i] = 3.4e38f; bi[i] = 0x7fffffff; }

  #pragma unroll 1
  for (int ch = 0; ch < 8; ++ch) {
    const int n0 = split * 1024 + ch * 128;

    float acc[8][8];
    #pragma unroll
    for (int i = 0; i < 8; ++i)
      #pragma unroll
      for (int j = 0; j < 8; ++j) acc[i][j] = 0.f;

    #pragma unroll 1
    for (int kt = 0; kt < 8; ++kt) {
      const int k0 = kt * 16;
      #pragma unroll
      for (int p = 0; p < 2; ++p) {
        const int r = arow + p * 64;
        float4 v = *reinterpret_cast<const float4*>(Z + (size_t)(m0 + r) * 128 + k0 + acol);
        As[acol + 0][r] = v.x; As[acol + 1][r] = v.y; As[acol + 2][r] = v.z; As[acol + 3][r] = v.w;
        float4 w = *reinterpret_cast<const float4*>(E + (size_t)(n0 + r) * 128 + k0 + acol);
        Bs[acol + 0][r] = w.x; Bs[acol + 1][r] = w.y; Bs[acol + 2][r] = w.z; Bs[acol + 3][r] = w.w;
      }
      __syncthreads();
      #pragma unroll
      for (int kk = 0; kk < 16; ++kk) {
        float a[8], b[8];
        float4 v;
        v = *reinterpret_cast<const float4*>(&As[kk][tr * 4]);      a[0]=v.x;a[1]=v.y;a[2]=v.z;a[3]=v.w;
        v = *reinterpret_cast<const float4*>(&As[kk][64 + tr * 4]); a[4]=v.x;a[5]=v.y;a[6]=v.z;a[7]=v.w;
        v = *reinterpret_cast<const float4*>(&Bs[kk][tc * 4]);      b[0]=v.x;b[1]=v.y;b[2]=v.z;b[3]=v.w;
        v = *reinterpret_cast<const float4*>(&Bs[kk][64 + tc * 4]); b[4]=v.x;b[5]=v.y;b[6]=v.z;b[7]=v.w;
        #pragma unroll
        for (int i = 0; i < 8; ++i)
          #pragma unroll
          for (int j = 0; j < 8; ++j)
            acc[i][j] = fmaf(a[i], b[j], acc[i][j]);
      }
      __syncthreads();
    }

    // fold this chunk (codes n0 .. n0+127) into running argmin, ascending order
    const float4 e20 = *reinterpret_cast<const float4*>(e2 + n0 + tc * 4);
    const float4 e21 = *reinterpret_cast<const float4*>(e2 + n0 + 64 + tc * 4);
    const float ev[8] = { e20.x, e20.y, e20.z, e20.w, e21.x, e21.y, e21.z, e21.w };
    #pragma unroll
    for (int i = 0; i < 8; ++i) {
      #pragma unroll
      for (int jh = 0; jh < 2; ++jh)
        #pragma unroll
        for (int j = 0; j < 4; ++j) {
          const int code = n0 + jh * 64 + tc * 4 + j;
          const float sc = ev[jh * 4 + j] - 2.f * acc[i][jh * 4 + j];
          if (sc < bv[i]) { bv[i] = sc; bi[i] = code; }
        }
    }
  }

  // cross-lane reduce over the 16 tc threads per row
  #pragma unroll
  for (int i = 0; i < 8; ++i) {
    float v = bv[i]; int ix = bi[i];
    #pragma unroll
    for (int m = 1; m < 16; m <<= 1) {
      float ov = __shfl_xor(v, m);
      int oi = __shfl_xor(ix, m);
      if (ov < v || (ov == v && oi < ix)) { v = ov; ix = oi; }
    }
    if (tc == 0) {
      const int row = m0 + (i >> 2) * 64 + tr * 4 + (i & 3);
      pval[(size_t)row * 4 + split] = v;
      pidx[(size_t)row * 4 + split] = ix;
    }
  }
}

// final argmin across 4 code-splits; histogram; index outputs
__global__ void vq_reduce(const float* __restrict__ pval, const int* __restrict__ pidx,
                          int* __restrict__ idxout, float* __restrict__ idxf,
                          int* __restrict__ counts)
{
  const int b = blockIdx.x * 256 + threadIdx.x;
  if (b >= B_ROWS) return;
  float best = 3.4e38f; int bi = 0;
  #pragma unroll
  for (int j = 0; j < 4; ++j) {            // ascending split -> lowest idx on tie
    float v = pval[(size_t)b * 4 + j];
    if (v < best) { best = v; bi = pidx[(size_t)b * 4 + j]; }
  }
  idxout[b] = bi;
  idxf[b] = (float)bi;
  atomicAdd(&counts[bi], 1);
}

// gather z_q -> z_q_st output; deterministic per-block commitment partial sums
__global__ __launch_bounds__(256)
void gather_commit(const int* __restrict__ idx, const float* __restrict__ E,
                   const float* __restrict__ ZE, float* __restrict__ ZQ,
                   float* __restrict__ cpart)
{
  __shared__ float red[4];
  const int b = blockIdx.x * 8 + (threadIdx.x >> 5);
  const int ch = threadIdx.x & 31;
  const int k = idx[b];
  float4 q = *reinterpret_cast<const float4*>(E + (size_t)k * 128 + ch * 4);
  float4 z = *reinterpret_cast<const float4*>(ZE + (size_t)b * 128 + ch * 4);
  *reinterpret_cast<float4*>(ZQ + (size_t)b * 128 + ch * 4) = q;
  float dx = q.x - z.x, dy = q.y - z.y, dz = q.z - z.z, dw = q.w - z.w;
  float s = dx * dx + dy * dy + dz * dz + dw * dw;
  #pragma unroll
  for (int m = 32; m; m >>= 1) s += __shfl_down(s, m);
  const int lane = threadIdx.x & 63, wid = threadIdx.x >> 6;
  if (lane == 0) red[wid] = s;
  __syncthreads();
  if (threadIdx.x == 0) cpart[blockIdx.x] = red[0] + red[1] + red[2] + red[3];
}

__global__ void e2_kernel(const float* __restrict__ E, float* __restrict__ e2)
{
  const int k = blockIdx.x * 256 + threadIdx.x;
  if (k >= KCODES) return;
  float s = 0.f;
  #pragma unroll 4
  for (int d = 0; d < 128; ++d) { float v = E[(size_t)k * 128 + d]; s += v * v; }
  e2[k] = s;
}

__global__ void zero_counts(int* counts)
{
  const int i = blockIdx.x * 256 + threadIdx.x;
  if (i < KCODES) counts[i] = 0;
}

__global__ void gelu_ew(float* __restrict__ p, int n)
{
  const int i = blockIdx.x * 256 + threadIdx.x;
  if (i < n) { float v = p[i]; p[i] = 0.5f * v * (1.f + erff(v * 0.70710678118654752f)); }
}

// tiny GEMM: V[Mx2] = T[Mx128] @ W6[128x2] + b6
__global__ void gemm_n2(const float* __restrict__ T, const float* __restrict__ W6,
                        const float* __restrict__ b6, float* __restrict__ V, int M)
{
  const int r = blockIdx.x * 256 + threadIdx.x;
  if (r >= M) return;
  float a0 = b6[0], a1 = b6[1];
  #pragma unroll 4
  for (int d = 0; d < 128; ++d) {
    float t = T[(size_t)r * 128 + d];
    a0 = fmaf(t, W6[d * 2 + 0], a0);
    a1 = fmaf(t, W6[d * 2 + 1], a1);
  }
  V[r * 2 + 0] = a0; V[r * 2 + 1] = a1;
}

__global__ void vel_gather(const int* __restrict__ idx, const float* __restrict__ V,
                           float* __restrict__ out)
{
  const int b = blockIdx.x * 256 + threadIdx.x;
  if (b >= B_ROWS) return;
  const int k = idx[b];
  out[b * 2 + 0] = V[k * 2 + 0];
  out[b * 2 + 1] = V[k * 2 + 1];
}

// deterministic scalar finish: commitment, perplexity, n_active
__global__ __launch_bounds__(256)
void stats_kernel(const float* __restrict__ cpart, const int* __restrict__ counts,
                  float* __restrict__ outs)
{
  __shared__ float sh[256];
  __shared__ float sh2[256];
  __shared__ int shi[256];
  const int t = threadIdx.x;
  float cs = 0.f;
  for (int i = t; i < 4096; i += 256) cs += cpart[i];
  float h = 0.f; int act = 0;
  for (int k = t; k < KCODES; k += 256) {
    float avg = counts[k] * (1.0f / 32768.0f);
    h += avg * logf(avg + 1e-10f);
    act += (avg > 0.001f) ? 1 : 0;
  }
  sh[t] = cs; sh2[t] = h; shi[t] = act;
  __syncthreads();
  for (int s = 128; s; s >>= 1) {
    if (t < s) { sh[t] += sh[t + s]; sh2[t] += sh2[t + s]; shi[t] += shi[t + s]; }
    __syncthreads();
  }
  if (t == 0) {
    outs[0] = 0.25f * sh[0] / (32768.0f * 128.0f);  // commitment
    outs[1] = expf(-sh2[0]);                        // perplexity
    outs[2] = (float)shi[0];                        // n_active
  }
}

extern "C" void kernel_launch(void* const* d_in, const int* in_sizes, int n_in,
                              void* d_out, int out_size, void* d_ws, size_t ws_size,
                              hipStream_t stream)
{
  const float* x   = (const float*)d_in[0];
  const float* W1  = (const float*)d_in[1];
  const float* b1  = (const float*)d_in[2];
  const float* g1  = (const float*)d_in[3];
  const float* be1 = (const float*)d_in[4];
  const float* W2  = (const float*)d_in[5];
  const float* b2  = (const float*)d_in[6];
  const float* g2  = (const float*)d_in[7];
  const float* be2 = (const float*)d_in[8];
  const float* W3  = (const float*)d_in[9];
  const float* b3  = (const float*)d_in[10];
  const float* emb = (const float*)d_in[11];
  const float* W4  = (const float*)d_in[12];
  const float* b4  = (const float*)d_in[13];
  const float* g3  = (const float*)d_in[14];
  const float* be3 = (const float*)d_in[15];
  const float* W5  = (const float*)d_in[16];
  const float* b5  = (const float*)d_in[17];
  const float* W6  = (const float*)d_in[18];
  const float* b6  = (const float*)d_in[19];

  float* out = (float*)d_out;
  float* o_vel  = out;                                   // [B,2]
  float* o_ze   = out + 65536;                           // [B,128]
  float* o_zq   = out + 65536 + B_ROWS * 128;            // [B,128]
  float* o_idx  = out + 65536 + 2 * B_ROWS * 128;        // [B] (as float)
  float* o_scal = o_idx + B_ROWS;                        // 3 scalars

  float* ws = (float*)d_ws;
  float* h1    = ws;                        // [B,512]  (dead after GEMM2)
  float* pval  = ws;                        // [B,4]    (live: VQ only)
  int*   pidx  = (int*)(ws + 1048576);      // [B,4]
  float* t1    = ws + 2097152;              // [4096,256]
  float* t2    = ws + 3145728;              // [4096,128]
  float* vv    = ws + 3670016;              // [4096,2]
  float* h2    = ws + 16777216;             // [B,256]
  float* e2    = ws + 25165824;             // [4096]
  int*   ind   = (int*)(ws + 25169920);     // [B]
  int*   cnt   = (int*)(ws + 25202688);     // [4096]
  float* cpart = ws + 25206784;             // [4096]

  // 1. init
  zero_counts<<<16, 256, 0, stream>>>(cnt);
  e2_kernel<<<16, 256, 0, stream>>>(emb, e2);

  // 2. encoder
  sgemm_f32<true><<<dim3(4, 256), 256, 0, stream>>>(x, W1, b1, h1, B_ROWS, 512, 1420);
  ln_gelu_kernel<<<B_ROWS, 256, 0, stream>>>(h1, h1, g1, be1, 512);
  sgemm_f32<false><<<dim3(2, 256), 256, 0, stream>>>(h1, W2, b2, h2, B_ROWS, 256, 512);
  ln_gelu_kernel<<<B_ROWS, 256, 0, stream>>>(h2, h2, g2, be2, 256);
  sgemm_f32<false><<<dim3(1, 256), 256, 0, stream>>>(h2, W3, b3, o_ze, B_ROWS, 128, 256);

  // 3. VQ: streaming argmin + reduce + gather + commitment partials + histogram
  vq_argmin<<<dim3(4, 256), 256, 0, stream>>>(o_ze, emb, e2, pval, pidx);
  vq_reduce<<<128, 256, 0, stream>>>(pval, pidx, ind, o_idx, cnt);
  gather_commit<<<4096, 256, 0, stream>>>(ind, emb, o_ze, o_zq, cpart);

  // 4. decoder on the 4096 distinct codes, then gather
  sgemm_f32<false><<<dim3(2, 32), 256, 0, stream>>>(emb, W4, b4, t1, KCODES, 256, 128);
  ln_gelu_kernel<<<KCODES, 256, 0, stream>>>(t1, t1, g3, be3, 256);
  sgemm_f32<false><<<dim3(1, 32), 256, 0, stream>>>(t1, W5, b5, t2, KCODES, 128, 256);
  gelu_ew<<<(KCODES * 128 + 255) / 256, 256, 0, stream>>>(t2, KCODES * 128);
  gemm_n2<<<(KCODES + 255) / 256, 256, 0, stream>>>(t2, W6, b6, vv, KCODES);
  vel_gather<<<128, 256, 0, stream>>>(ind, vv, o_vel);

  // 5. scalars
  stats_kernel<<<1, 256, 0, stream>>>(cpart, cnt, o_scal);
}

// Round 6
// 1125.091 us; speedup vs baseline: 1.7003x; 1.3749x over previous
//
#include <hip/hip_runtime.h>

#define B_ROWS 32768
#define KCODES 4096

typedef float f32x4 __attribute__((ext_vector_type(4)));
typedef _Float16 f16x8 __attribute__((ext_vector_type(8)));
typedef _Float16 f16x4 __attribute__((ext_vector_type(4)));

struct Split { _Float16 h, m; };

// split f32 -> fp16 head + fp16 scaled residual (exact-repr residual, x256 keeps
// it in fp16 normal range; C = hi + mid/256 recombines to f32-grade accuracy)
__device__ __forceinline__ Split split2(float v)
{
  Split s;
  s.h = (_Float16)v;
  s.m = (_Float16)((v - (float)s.h) * 256.f);
  return s;
}

// ---------------------------------------------------------------------------
// fp16-split MFMA GEMM: C[M][N] = A[M][K](f32) @ B[K][N] + bias, f32-grade.
// B pre-supplied as two fp16 arrays Bh/Bm, TRANSPOSED [N][Kp] (Kp = K padded
// to 32, zero-filled). 256 thr / 4 waves, block tile 128x128, wave 64x64,
// BK=32 (one mfma_f32_16x16x32_f16 per k-tile per 16x16 tile per product).
// 3 products: hi += A1B1 ; mid += A1*B2s + A2s*B1 ; C = hi + mid*2^-8.
// LDS rows padded to 40 halves (80 B): 16B-aligned b128, uniform bank spread.
// ---------------------------------------------------------------------------
template<bool KTAIL>
__global__ __launch_bounds__(256)
void hgemm4(const float* __restrict__ A, const _Float16* __restrict__ Bh,
            const _Float16* __restrict__ Bm, const float* __restrict__ bias,
            float* __restrict__ C, int M, int N, int K, int Kp)
{
  __shared__ _Float16 As1[128 * 40];
  __shared__ _Float16 As2[128 * 40];
  __shared__ _Float16 Bs1[128 * 40];
  __shared__ _Float16 Bs2[128 * 40];

  const int tid  = threadIdx.x;
  const int lane = tid & 63;
  const int wid  = tid >> 6;
  const int l15  = lane & 15;
  const int lg   = lane >> 4;
  const int wm   = (wid >> 1) * 64;     // wave row offset in tile
  const int wn   = (wid & 1) * 64;      // wave col offset in tile
  const int m0   = blockIdx.y * 128;
  const int n0   = blockIdx.x * 128;

  f32x4 hi[4][4], mid[4][4];
  #pragma unroll
  for (int i = 0; i < 4; ++i)
    #pragma unroll
    for (int j = 0; j < 4; ++j) { hi[i][j] = (f32x4)0.f; mid[i][j] = (f32x4)0.f; }

  const int sar = tid >> 2;            // A-stage row 0..63 (+64)
  const int sac = (tid & 3) << 2;      // A-stage float col 0,4,8,12 (+16)
  const int sbn = tid >> 1;            // B-stage n 0..127
  const int sbk = (tid & 1) << 4;      // B-stage k-half 0/16

  const int nk = (K + 31) >> 5;
  #pragma unroll 1
  for (int kt = 0; kt < nk; ++kt) {
    const int k0 = kt << 5;
    // ---- stage A (f32 -> split fp16), 128x32 ----
    #pragma unroll
    for (int p = 0; p < 2; ++p)
      #pragma unroll
      for (int q = 0; q < 2; ++q) {
        const int r  = sar + p * 64;
        const int kk = sac + q * 16;
        float4 v = make_float4(0.f, 0.f, 0.f, 0.f);
        if (!KTAIL || (k0 + kk) < K)     // K % 4 == 0 so float4 fully valid
          v = *reinterpret_cast<const float4*>(A + (size_t)(m0 + r) * K + k0 + kk);
        const Split sx = split2(v.x), sy = split2(v.y), sz = split2(v.z), sw = split2(v.w);
        f16x4 h, m;
        h[0] = sx.h; h[1] = sy.h; h[2] = sz.h; h[3] = sw.h;
        m[0] = sx.m; m[1] = sy.m; m[2] = sz.m; m[3] = sw.m;
        *reinterpret_cast<f16x4*>(&As1[r * 40 + kk]) = h;
        *reinterpret_cast<f16x4*>(&As2[r * 40 + kk]) = m;
      }
    // ---- stage B (pre-split fp16 [N][Kp]), 128x32 halves x2 ----
    {
      const size_t gb = (size_t)(n0 + sbn) * Kp + k0 + sbk;
      const int lb = sbn * 40 + sbk;
      *reinterpret_cast<uint4*>(&Bs1[lb])     = *reinterpret_cast<const uint4*>(Bh + gb);
      *reinterpret_cast<uint4*>(&Bs1[lb + 8]) = *reinterpret_cast<const uint4*>(Bh + gb + 8);
      *reinterpret_cast<uint4*>(&Bs2[lb])     = *reinterpret_cast<const uint4*>(Bm + gb);
      *reinterpret_cast<uint4*>(&Bs2[lb + 8]) = *reinterpret_cast<const uint4*>(Bm + gb + 8);
    }
    __syncthreads();

    f16x8 a[4], b[4], b2[4];
    #pragma unroll
    for (int i = 0; i < 4; ++i)
      a[i] = *reinterpret_cast<const f16x8*>(&As1[(wm + i * 16 + l15) * 40 + 8 * lg]);
    #pragma unroll
    for (int j = 0; j < 4; ++j)
      b[j] = *reinterpret_cast<const f16x8*>(&Bs1[(wn + j * 16 + l15) * 40 + 8 * lg]);
    #pragma unroll
    for (int i = 0; i < 4; ++i)
      #pragma unroll
      for (int j = 0; j < 4; ++j)
        hi[i][j] = __builtin_amdgcn_mfma_f32_16x16x32_f16(a[i], b[j], hi[i][j], 0, 0, 0);
    #pragma unroll
    for (int j = 0; j < 4; ++j)
      b2[j] = *reinterpret_cast<const f16x8*>(&Bs2[(wn + j * 16 + l15) * 40 + 8 * lg]);
    #pragma unroll
    for (int i = 0; i < 4; ++i)
      #pragma unroll
      for (int j = 0; j < 4; ++j)
        mid[i][j] = __builtin_amdgcn_mfma_f32_16x16x32_f16(a[i], b2[j], mid[i][j], 0, 0, 0);
    #pragma unroll
    for (int i = 0; i < 4; ++i)
      a[i] = *reinterpret_cast<const f16x8*>(&As2[(wm + i * 16 + l15) * 40 + 8 * lg]);
    #pragma unroll
    for (int i = 0; i < 4; ++i)
      #pragma unroll
      for (int j = 0; j < 4; ++j)
        mid[i][j] = __builtin_amdgcn_mfma_f32_16x16x32_f16(a[i], b[j], mid[i][j], 0, 0, 0);
    __syncthreads();
  }

  // epilogue: D[r][c] with r = 4*lg + reg, c = l15 (m89-verified layout)
  #pragma unroll
  for (int i = 0; i < 4; ++i)
    #pragma unroll
    for (int j = 0; j < 4; ++j) {
      const int col = n0 + wn + j * 16 + l15;
      const float bs = bias[col];
      #pragma unroll
      for (int r = 0; r < 4; ++r) {
        const int row = m0 + wm + i * 16 + 4 * lg + r;
        C[(size_t)row * N + col] = hi[i][j][r] + 0.00390625f * mid[i][j][r] + bs;
      }
    }
}

// ---------------------------------------------------------------------------
// VQ argmin via fp16-split MFMA. Block = 64 rows x 1024 codes (grid 4 x 512).
// Z-tile (64x128) split-staged ONCE into resident LDS; 8 chunks of 128 codes,
// each 4 k-tiles of 32. score = e2[c] - 2*(hi + mid*2^-8); running per-row
// (best,idx), lowest-index tie-break; cross-lane reduce in 16-lane groups.
// ---------------------------------------------------------------------------
__global__ __launch_bounds__(256)
void vq_mfma(const float* __restrict__ Z, const _Float16* __restrict__ E1,
             const _Float16* __restrict__ E2, const float* __restrict__ e2,
             float* __restrict__ pval, int* __restrict__ pidx)
{
  __shared__ _Float16 Zs1[64 * 136];
  __shared__ _Float16 Zs2[64 * 136];
  __shared__ _Float16 Es1[128 * 40];
  __shared__ _Float16 Es2[128 * 40];

  const int tid  = threadIdx.x;
  const int lane = tid & 63;
  const int wid  = tid >> 6;          // wave col slice: wid*32
  const int l15  = lane & 15;
  const int lg   = lane >> 4;
  const int wn   = wid * 32;
  const int m0   = blockIdx.y * 64;
  const int split = blockIdx.x;       // 0..3

  // stage Z tile once: 64 rows x 128 k
  {
    const int zr = tid >> 2;
    #pragma unroll
    for (int q = 0; q < 8; ++q) {
      const int kk = ((tid & 3) << 2) + (q << 4);
      float4 v = *reinterpret_cast<const float4*>(Z + (size_t)(m0 + zr) * 128 + kk);
      const Split sx = split2(v.x), sy = split2(v.y), sz = split2(v.z), sw = split2(v.w);
      f16x4 h, m;
      h[0] = sx.h; h[1] = sy.h; h[2] = sz.h; h[3] = sw.h;
      m[0] = sx.m; m[1] = sy.m; m[2] = sz.m; m[3] = sw.m;
      *reinterpret_cast<f16x4*>(&Zs1[zr * 136 + kk]) = h;
      *reinterpret_cast<f16x4*>(&Zs2[zr * 136 + kk]) = m;
    }
  }

  float bv[16];
  int   bi[16];
  #pragma unroll
  for (int s = 0; s < 16; ++s) { bv[s] = 3.4e38f; bi[s] = 0x7fffffff; }

  const int sbn = tid >> 1;
  const int sbk = (tid & 1) << 4;

  #pragma unroll 1
  for (int ch = 0; ch < 8; ++ch) {
    const int n0 = split * 1024 + ch * 128;
    f32x4 hi[4][2], mid[4][2];
    #pragma unroll
    for (int i = 0; i < 4; ++i)
      #pragma unroll
      for (int j = 0; j < 2; ++j) { hi[i][j] = (f32x4)0.f; mid[i][j] = (f32x4)0.f; }

    #pragma unroll 1
    for (int kt = 0; kt < 4; ++kt) {
      const int k0 = kt << 5;
      {
        const size_t gb = (size_t)(n0 + sbn) * 128 + k0 + sbk;
        const int lb = sbn * 40 + sbk;
        *reinterpret_cast<uint4*>(&Es1[lb])     = *reinterpret_cast<const uint4*>(E1 + gb);
        *reinterpret_cast<uint4*>(&Es1[lb + 8]) = *reinterpret_cast<const uint4*>(E1 + gb + 8);
        *reinterpret_cast<uint4*>(&Es2[lb])     = *reinterpret_cast<const uint4*>(E2 + gb);
        *reinterpret_cast<uint4*>(&Es2[lb + 8]) = *reinterpret_cast<const uint4*>(E2 + gb + 8);
      }
      __syncthreads();

      f16x8 a[4], b[2], b2[2];
      #pragma unroll
      for (int i = 0; i < 4; ++i)
        a[i] = *reinterpret_cast<const f16x8*>(&Zs1[(i * 16 + l15) * 136 + k0 + 8 * lg]);
      #pragma unroll
      for (int j = 0; j < 2; ++j)
        b[j] = *reinterpret_cast<const f16x8*>(&Es1[(wn + j * 16 + l15) * 40 + 8 * lg]);
      #pragma unroll
      for (int i = 0; i < 4; ++i)
        #pragma unroll
        for (int j = 0; j < 2; ++j)
          hi[i][j] = __builtin_amdgcn_mfma_f32_16x16x32_f16(a[i], b[j], hi[i][j], 0, 0, 0);
      #pragma unroll
      for (int j = 0; j < 2; ++j)
        b2[j] = *reinterpret_cast<const f16x8*>(&Es2[(wn + j * 16 + l15) * 40 + 8 * lg]);
      #pragma unroll
      for (int i = 0; i < 4; ++i)
        #pragma unroll
        for (int j = 0; j < 2; ++j)
          mid[i][j] = __builtin_amdgcn_mfma_f32_16x16x32_f16(a[i], b2[j], mid[i][j], 0, 0, 0);
      #pragma unroll
      for (int i = 0; i < 4; ++i)
        a[i] = *reinterpret_cast<const f16x8*>(&Zs2[(i * 16 + l15) * 136 + k0 + 8 * lg]);
      #pragma unroll
      for (int i = 0; i < 4; ++i)
        #pragma unroll
        for (int j = 0; j < 2; ++j)
          mid[i][j] = __builtin_amdgcn_mfma_f32_16x16x32_f16(a[i], b[j], mid[i][j], 0, 0, 0);
      __syncthreads();
    }

    // fold chunk into running argmin (ascending code order per lane; ties -> lowest idx)
    #pragma unroll
    for (int j = 0; j < 2; ++j) {
      const int c = n0 + wn + j * 16 + l15;
      const float ec = e2[c];
      #pragma unroll
      for (int i = 0; i < 4; ++i)
        #pragma unroll
        for (int r = 0; r < 4; ++r) {
          const float sc = ec - 2.f * (hi[i][j][r] + 0.00390625f * mid[i][j][r]);
          if (sc < bv[i * 4 + r]) { bv[i * 4 + r] = sc; bi[i * 4 + r] = c; }
        }
    }
  }

  // cross-lane reduce over the 16 cols held by each 16-lane group
  #pragma unroll
  for (int s = 0; s < 16; ++s) {
    float v = bv[s]; int ix = bi[s];
    #pragma unroll
    for (int m = 1; m < 16; m <<= 1) {
      const float ov = __shfl_xor(v, m);
      const int   oi = __shfl_xor(ix, m);
      if (ov < v || (ov == v && oi < ix)) { v = ov; ix = oi; }
    }
    if (l15 == 0) {
      const int row = m0 + (s >> 2) * 16 + 4 * lg + (s & 3);
      pval[(size_t)row * 16 + split * 4 + wid] = v;
      pidx[(size_t)row * 16 + split * 4 + wid] = ix;
    }
  }
}

// ---------------------------------------------------------------------------
// weight prep: W [K][N] f32 -> Bh/Bm [N][Kp] fp16 (transposed, zero-padded)
// N must be a power of two (nshift/nmask). Coalesced reads along n.
// ---------------------------------------------------------------------------
__global__ void prep_wT(const float* __restrict__ W, _Float16* __restrict__ Bh,
                        _Float16* __restrict__ Bm, int K, int N, int nshift,
                        int nmask, int Kp)
{
  const int i = blockIdx.x * 256 + threadIdx.x;
  if (i >= N * Kp) return;
  const int n = i & nmask;
  const int k = i >> nshift;
  const float v = (k < K) ? W[(size_t)k * N + n] : 0.f;
  const Split s = split2(v);
  Bh[(size_t)n * Kp + k] = s.h;
  Bm[(size_t)n * Kp + k] = s.m;
}

// emb [4096][128] f32 -> E1/E2 fp16 (already row-major [n][k])
__global__ void prep_emb(const float* __restrict__ E, _Float16* __restrict__ E1,
                         _Float16* __restrict__ E2)
{
  const int i = blockIdx.x * 256 + threadIdx.x;
  const Split s = split2(E[i]);
  E1[i] = s.h; E2[i] = s.m;
}

// ---------------------------------------------------------------------------
// Row-wise LayerNorm (+affine) + exact GELU (erf). One block (256 thr) per row.
// ---------------------------------------------------------------------------
__global__ __launch_bounds__(256)
void ln_gelu_kernel(const float* __restrict__ in, float* __restrict__ out,
                    const float* __restrict__ g, const float* __restrict__ be, int Wd)
{
  __shared__ float rs[4], rs2[4];
  const int row = blockIdx.x;
  const float* x = in + (size_t)row * Wd;
  float s = 0.f, s2 = 0.f;
  for (int c = threadIdx.x; c < Wd; c += 256) { float v = x[c]; s += v; s2 += v * v; }
  #pragma unroll
  for (int m = 32; m; m >>= 1) { s += __shfl_down(s, m); s2 += __shfl_down(s2, m); }
  const int lane = threadIdx.x & 63, wv = threadIdx.x >> 6;
  if (lane == 0) { rs[wv] = s; rs2[wv] = s2; }
  __syncthreads();
  if (threadIdx.x == 0) {
    float S = rs[0] + rs[1] + rs[2] + rs[3];
    float S2 = rs2[0] + rs2[1] + rs2[2] + rs2[3];
    float mean = S / Wd;
    float var = S2 / Wd - mean * mean;
    rs[0] = mean; rs2[0] = 1.0f / sqrtf(var + 1e-5f);
  }
  __syncthreads();
  const float mean = rs[0], inv = rs2[0];
  for (int c = threadIdx.x; c < Wd; c += 256) {
    float v = (x[c] - mean) * inv * g[c] + be[c];
    out[(size_t)row * Wd + c] = 0.5f * v * (1.f + erff(v * 0.70710678118654752f));
  }
}

// final argmin across 16 (split,wave) partials; histogram; index outputs
__global__ void vq_reduce(const float* __restrict__ pval, const int* __restrict__ pidx,
                          int* __restrict__ idxout, float* __restrict__ idxf,
                          int* __restrict__ counts)
{
  const int b = blockIdx.x * 256 + threadIdx.x;
  if (b >= B_ROWS) return;
  float best = 3.4e38f; int bix = 0x7fffffff;
  #pragma unroll
  for (int j = 0; j < 16; ++j) {
    const float v = pval[(size_t)b * 16 + j];
    const int   ii = pidx[(size_t)b * 16 + j];
    if (v < best || (v == best && ii < bix)) { best = v; bix = ii; }
  }
  idxout[b] = bix;
  idxf[b] = (float)bix;
  atomicAdd(&counts[bix], 1);
}

// gather z_q -> z_q_st output; deterministic per-block commitment partial sums
__global__ __launch_bounds__(256)
void gather_commit(const int* __restrict__ idx, const float* __restrict__ E,
                   const float* __restrict__ ZE, float* __restrict__ ZQ,
                   float* __restrict__ cpart)
{
  __shared__ float red[4];
  const int b = blockIdx.x * 8 + (threadIdx.x >> 5);
  const int ch = threadIdx.x & 31;
  const int k = idx[b];
  float4 q = *reinterpret_cast<const float4*>(E + (size_t)k * 128 + ch * 4);
  float4 z = *reinterpret_cast<const float4*>(ZE + (size_t)b * 128 + ch * 4);
  *reinterpret_cast<float4*>(ZQ + (size_t)b * 128 + ch * 4) = q;
  float dx = q.x - z.x, dy = q.y - z.y, dz = q.z - z.z, dw = q.w - z.w;
  float s = dx * dx + dy * dy + dz * dz + dw * dw;
  #pragma unroll
  for (int m = 32; m; m >>= 1) s += __shfl_down(s, m);
  const int lane = threadIdx.x & 63, wv = threadIdx.x >> 6;
  if (lane == 0) red[wv] = s;
  __syncthreads();
  if (threadIdx.x == 0) cpart[blockIdx.x] = red[0] + red[1] + red[2] + red[3];
}

__global__ void e2_kernel(const float* __restrict__ E, float* __restrict__ e2)
{
  const int k = blockIdx.x * 256 + threadIdx.x;
  if (k >= KCODES) return;
  float s = 0.f;
  #pragma unroll 4
  for (int d = 0; d < 128; ++d) { float v = E[(size_t)k * 128 + d]; s += v * v; }
  e2[k] = s;
}

__global__ void zero_counts(int* counts)
{
  const int i = blockIdx.x * 256 + threadIdx.x;
  if (i < KCODES) counts[i] = 0;
}

__global__ void gelu_ew(float* __restrict__ p, int n)
{
  const int i = blockIdx.x * 256 + threadIdx.x;
  if (i < n) { float v = p[i]; p[i] = 0.5f * v * (1.f + erff(v * 0.70710678118654752f)); }
}

// tiny GEMM: V[Mx2] = T[Mx128] @ W6[128x2] + b6
__global__ void gemm_n2(const float* __restrict__ T, const float* __restrict__ W6,
                        const float* __restrict__ b6, float* __restrict__ V, int M)
{
  const int r = blockIdx.x * 256 + threadIdx.x;
  if (r >= M) return;
  float a0 = b6[0], a1 = b6[1];
  #pragma unroll 4
  for (int d = 0; d < 128; ++d) {
    float t = T[(size_t)r * 128 + d];
    a0 = fmaf(t, W6[d * 2 + 0], a0);
    a1 = fmaf(t, W6[d * 2 + 1], a1);
  }
  V[r * 2 + 0] = a0; V[r * 2 + 1] = a1;
}

__global__ void vel_gather(const int* __restrict__ idx, const float* __restrict__ V,
                           float* __restrict__ out)
{
  const int b = blockIdx.x * 256 + threadIdx.x;
  if (b >= B_ROWS) return;
  const int k = idx[b];
  out[b * 2 + 0] = V[k * 2 + 0];
  out[b * 2 + 1] = V[k * 2 + 1];
}

// deterministic scalar finish: commitment, perplexity, n_active
__global__ __launch_bounds__(256)
void stats_kernel(const float* __restrict__ cpart, const int* __restrict__ counts,
                  float* __restrict__ outs)
{
  __shared__ float sh[256];
  __shared__ float sh2[256];
  __shared__ int shi[256];
  const int t = threadIdx.x;
  float cs = 0.f;
  for (int i = t; i < 4096; i += 256) cs += cpart[i];
  float h = 0.f; int act = 0;
  for (int k = t; k < KCODES; k += 256) {
    float avg = counts[k] * (1.0f / 32768.0f);
    h += avg * logf(avg + 1e-10f);
    act += (avg > 0.001f) ? 1 : 0;
  }
  sh[t] = cs; sh2[t] = h; shi[t] = act;
  __syncthreads();
  for (int s = 128; s; s >>= 1) {
    if (t < s) { sh[t] += sh[t + s]; sh2[t] += sh2[t + s]; shi[t] += shi[t + s]; }
    __syncthreads();
  }
  if (t == 0) {
    outs[0] = 0.25f * sh[0] / (32768.0f * 128.0f);
    outs[1] = expf(-sh2[0]);
    outs[2] = (float)shi[0];
  }
}

extern "C" void kernel_launch(void* const* d_in, const int* in_sizes, int n_in,
                              void* d_out, int out_size, void* d_ws, size_t ws_size,
                              hipStream_t stream)
{
  const float* x   = (const float*)d_in[0];
  const float* W1  = (const float*)d_in[1];
  const float* b1  = (const float*)d_in[2];
  const float* g1  = (const float*)d_in[3];
  const float* be1 = (const float*)d_in[4];
  const float* W2  = (const float*)d_in[5];
  const float* b2  = (const float*)d_in[6];
  const float* g2  = (const float*)d_in[7];
  const float* be2 = (const float*)d_in[8];
  const float* W3  = (const float*)d_in[9];
  const float* b3  = (const float*)d_in[10];
  const float* emb = (const float*)d_in[11];
  const float* W4  = (const float*)d_in[12];
  const float* b4  = (const float*)d_in[13];
  const float* g3  = (const float*)d_in[14];
  const float* be3 = (const float*)d_in[15];
  const float* W5  = (const float*)d_in[16];
  const float* b5  = (const float*)d_in[17];
  const float* W6  = (const float*)d_in[18];
  const float* b6  = (const float*)d_in[19];

  float* out = (float*)d_out;
  float* o_vel  = out;                                   // [B,2]
  float* o_ze   = out + 65536;                           // [B,128]
  float* o_zq   = out + 65536 + B_ROWS * 128;            // [B,128]
  float* o_idx  = out + 65536 + 2 * B_ROWS * 128;        // [B] (as float)
  float* o_scal = o_idx + B_ROWS;                        // 3 scalars

  float* ws = (float*)d_ws;
  float* h1    = ws;                        // [B,512]  (enc phase)
  float* pval  = ws;                        // [B,16]   (vq phase, h1 dead)
  int*   pidx  = (int*)(ws + 550000);       // [B,16]
  float* t1    = ws + 2100000;              // [4096,256]
  float* t2    = ws + 3150000;              // [4096,128]
  float* vv    = ws + 3700000;              // [4096,2]
  float* h2    = ws + 16777216;             // [B,256]
  float* e2    = ws + 25165824;             // [4096]
  int*   ind   = (int*)(ws + 25169920);     // [B]
  int*   cnt   = (int*)(ws + 25202688);     // [4096]
  float* cpart = ws + 25206784;             // [4096]

  // fp16 region (16B-aligned: 25300000*4 % 16 == 0); all sizes multiple of 8
  _Float16* hb  = (_Float16*)(ws + 25300000);
  _Float16* E1  = hb;                       // 4096*128
  _Float16* E2  = E1 + 524288;
  _Float16* W1a = E2 + 524288;              // 512*1440
  _Float16* W1b = W1a + 737280;
  _Float16* W2a = W1b + 737280;             // 256*512
  _Float16* W2b = W2a + 131072;
  _Float16* W3a = W2b + 131072;             // 128*256
  _Float16* W3b = W3a + 32768;
  _Float16* W4a = W3b + 32768;              // 256*128
  _Float16* W4b = W4a + 32768;
  _Float16* W5a = W4b + 32768;              // 128*256
  _Float16* W5b = W5a + 32768;
  // end ≈ ws + 26.8M floats ≈ 107 MB

  // 1. init + weight prep (runs every call; ~3 MB total)
  zero_counts<<<16, 256, 0, stream>>>(cnt);
  e2_kernel<<<16, 256, 0, stream>>>(emb, e2);
  prep_emb<<<2048, 256, 0, stream>>>(emb, E1, E2);
  prep_wT<<<2880, 256, 0, stream>>>(W1, W1a, W1b, 1420, 512, 9, 511, 1440);
  prep_wT<<<512, 256, 0, stream>>>(W2, W2a, W2b, 512, 256, 8, 255, 512);
  prep_wT<<<128, 256, 0, stream>>>(W3, W3a, W3b, 256, 128, 7, 127, 256);
  prep_wT<<<128, 256, 0, stream>>>(W4, W4a, W4b, 128, 256, 8, 255, 128);
  prep_wT<<<128, 256, 0, stream>>>(W5, W5a, W5b, 256, 128, 7, 127, 256);

  // 2. encoder (fp16-split MFMA, f32-grade)
  hgemm4<true><<<dim3(4, 256), 256, 0, stream>>>(x, W1a, W1b, b1, h1, B_ROWS, 512, 1420, 1440);
  ln_gelu_kernel<<<B_ROWS, 256, 0, stream>>>(h1, h1, g1, be1, 512);
  hgemm4<false><<<dim3(2, 256), 256, 0, stream>>>(h1, W2a, W2b, b2, h2, B_ROWS, 256, 512, 512);
  ln_gelu_kernel<<<B_ROWS, 256, 0, stream>>>(h2, h2, g2, be2, 256);
  hgemm4<false><<<dim3(1, 256), 256, 0, stream>>>(h2, W3a, W3b, b3, o_ze, B_ROWS, 128, 256, 256);

  // 3. VQ
  vq_mfma<<<dim3(4, 512), 256, 0, stream>>>(o_ze, E1, E2, e2, pval, pidx);
  vq_reduce<<<128, 256, 0, stream>>>(pval, pidx, ind, o_idx, cnt);
  gather_commit<<<4096, 256, 0, stream>>>(ind, emb, o_ze, o_zq, cpart);

  // 4. decoder on the 4096 distinct codes, then gather
  hgemm4<false><<<dim3(2, 32), 256, 0, stream>>>(emb, W4a, W4b, b4, t1, KCODES, 256, 128, 128);
  ln_gelu_kernel<<<KCODES, 256, 0, stream>>>(t1, t1, g3, be3, 256);
  hgemm4<false><<<dim3(1, 32), 256, 0, stream>>>(t1, W5a, W5b, b5, t2, KCODES, 128, 256, 256);
  gelu_ew<<<(KCODES * 128 + 255) / 256, 256, 0, stream>>>(t2, KCODES * 128);
  gemm_n2<<<(KCODES + 255) / 256, 256, 0, stream>>>(t2, W6, b6, vv, KCODES);
  vel_gather<<<128, 256, 0, stream>>>(ind, vv, o_vel);

  // 5. scalars
  stats_kernel<<<1, 256, 0, stream>>>(cpart, cnt, o_scal);
}

// Round 7
// 1063.738 us; speedup vs baseline: 1.7984x; 1.0577x over previous
//
#include <hip/hip_runtime.h>

#define B_ROWS 32768
#define KCODES 4096

typedef float f32x4 __attribute__((ext_vector_type(4)));
typedef _Float16 f16x8 __attribute__((ext_vector_type(8)));
typedef _Float16 f16x4 __attribute__((ext_vector_type(4)));

struct Split { _Float16 h, m; };

// split f32 -> fp16 head + fp16 scaled residual (residual x256 stays normal;
// C = hi + mid/256 recombines to f32-grade accuracy)
__device__ __forceinline__ Split split2(float v)
{
  Split s;
  s.h = (_Float16)v;
  s.m = (_Float16)((v - (float)s.h) * 256.f);
  return s;
}

// ---------------------------------------------------------------------------
// fp16-split MFMA GEMM. Block tile 128x64, 4 waves of 64x32 (acc = 64 f32/lane
// vs round-6's 128 -> occupancy 1 -> 3 waves/SIMD). BK=32.
// SPLITA=true : A is f32 [M][K] (GEMM1; split in LDS staging, K-tail guarded)
// SPLITA=false: A pre-split fp16 pair Ah/Am, row stride Astr halves.
// B pre-split fp16 [N][Kp] (Kp%32==0, zero-padded).
// hi += A1B1 ; mid += A1*B2s + A2s*B1 ; C = hi + mid*2^-8 + bias.
// LDS row stride 40 halves (80B): 16B-aligned b128 reads, 2-way banks.
// ---------------------------------------------------------------------------
template<bool SPLITA>
__global__ __launch_bounds__(256, 3)
void hgemm(const float* __restrict__ Af, const _Float16* __restrict__ Ah,
           const _Float16* __restrict__ Am, int Astr,
           const _Float16* __restrict__ Bh, const _Float16* __restrict__ Bm,
           const float* __restrict__ bias, float* __restrict__ C,
           int M, int N, int K, int Kp)
{
  __shared__ _Float16 As1[128 * 40];
  __shared__ _Float16 As2[128 * 40];
  __shared__ _Float16 Bs1[64 * 40];
  __shared__ _Float16 Bs2[64 * 40];

  const int tid  = threadIdx.x;
  const int lane = tid & 63;
  const int wid  = tid >> 6;
  const int l15  = lane & 15;
  const int lg   = lane >> 4;
  const int wm   = (wid >> 1) * 64;
  const int wn   = (wid & 1) * 32;
  const int m0   = blockIdx.y * 128;
  const int n0   = blockIdx.x * 64;

  f32x4 hi[4][2], mid[4][2];
  #pragma unroll
  for (int i = 0; i < 4; ++i)
    #pragma unroll
    for (int j = 0; j < 2; ++j) { hi[i][j] = (f32x4)0.f; mid[i][j] = (f32x4)0.f; }

  const int sar = tid >> 1;           // 0..127
  const int sak = (tid & 1) << 4;     // 0/16 (halves)
  const int sbn = tid >> 2;           // 0..63
  const int sbk = (tid & 3) << 3;     // 0,8,16,24 (halves)

  const int nk = Kp >> 5;
  #pragma unroll 1
  for (int kt = 0; kt < nk; ++kt) {
    const int k0 = kt << 5;
    // ---- stage A 128x32 ----
    if (SPLITA) {
      #pragma unroll
      for (int q = 0; q < 4; ++q) {
        const int c = k0 + sak + 4 * q;
        float4 v = make_float4(0.f, 0.f, 0.f, 0.f);
        if (c < K) v = *reinterpret_cast<const float4*>(Af + (size_t)(m0 + sar) * K + c);
        const Split sx = split2(v.x), sy = split2(v.y), sz = split2(v.z), sw = split2(v.w);
        f16x4 h, m;
        h[0] = sx.h; h[1] = sy.h; h[2] = sz.h; h[3] = sw.h;
        m[0] = sx.m; m[1] = sy.m; m[2] = sz.m; m[3] = sw.m;
        *reinterpret_cast<f16x4*>(&As1[sar * 40 + sak + 4 * q]) = h;
        *reinterpret_cast<f16x4*>(&As2[sar * 40 + sak + 4 * q]) = m;
      }
    } else {
      const size_t gA = (size_t)(m0 + sar) * Astr + k0 + sak;
      const int lA = sar * 40 + sak;
      *reinterpret_cast<uint4*>(&As1[lA])     = *reinterpret_cast<const uint4*>(Ah + gA);
      *reinterpret_cast<uint4*>(&As1[lA + 8]) = *reinterpret_cast<const uint4*>(Ah + gA + 8);
      *reinterpret_cast<uint4*>(&As2[lA])     = *reinterpret_cast<const uint4*>(Am + gA);
      *reinterpret_cast<uint4*>(&As2[lA + 8]) = *reinterpret_cast<const uint4*>(Am + gA + 8);
    }
    // ---- stage B 64x32 ----
    {
      const size_t gB = (size_t)(n0 + sbn) * Kp + k0 + sbk;
      const int lB = sbn * 40 + sbk;
      *reinterpret_cast<uint4*>(&Bs1[lB]) = *reinterpret_cast<const uint4*>(Bh + gB);
      *reinterpret_cast<uint4*>(&Bs2[lB]) = *reinterpret_cast<const uint4*>(Bm + gB);
    }
    __syncthreads();

    f16x8 a1[4], b[2];
    #pragma unroll
    for (int i = 0; i < 4; ++i)
      a1[i] = *reinterpret_cast<const f16x8*>(&As1[(wm + i * 16 + l15) * 40 + 8 * lg]);
    #pragma unroll
    for (int j = 0; j < 2; ++j)
      b[j] = *reinterpret_cast<const f16x8*>(&Bs1[(wn + j * 16 + l15) * 40 + 8 * lg]);
    #pragma unroll
    for (int i = 0; i < 4; ++i)
      #pragma unroll
      for (int j = 0; j < 2; ++j)
        hi[i][j] = __builtin_amdgcn_mfma_f32_16x16x32_f16(a1[i], b[j], hi[i][j], 0, 0, 0);
    #pragma unroll
    for (int i = 0; i < 4; ++i) {
      const f16x8 a2 = *reinterpret_cast<const f16x8*>(&As2[(wm + i * 16 + l15) * 40 + 8 * lg]);
      #pragma unroll
      for (int j = 0; j < 2; ++j)
        mid[i][j] = __builtin_amdgcn_mfma_f32_16x16x32_f16(a2, b[j], mid[i][j], 0, 0, 0);
    }
    #pragma unroll
    for (int j = 0; j < 2; ++j)
      b[j] = *reinterpret_cast<const f16x8*>(&Bs2[(wn + j * 16 + l15) * 40 + 8 * lg]);
    #pragma unroll
    for (int i = 0; i < 4; ++i)
      #pragma unroll
      for (int j = 0; j < 2; ++j)
        mid[i][j] = __builtin_amdgcn_mfma_f32_16x16x32_f16(a1[i], b[j], mid[i][j], 0, 0, 0);
    __syncthreads();
  }

  // epilogue: D row = 4*lg + r, col = l15 (m89-verified layout)
  #pragma unroll
  for (int i = 0; i < 4; ++i)
    #pragma unroll
    for (int j = 0; j < 2; ++j) {
      const int col = n0 + wn + j * 16 + l15;
      const float bs = bias[col];
      #pragma unroll
      for (int r = 0; r < 4; ++r) {
        const int row = m0 + wm + i * 16 + 4 * lg + r;
        C[(size_t)row * N + col] = hi[i][j][r] + 0.00390625f * mid[i][j][r] + bs;
      }
    }
}

// ---------------------------------------------------------------------------
// Row LayerNorm + exact GELU, writing split fp16 pair IN-PLACE over the f32
// row: halves [0..Wd) = head, [Wd..2Wd) = scaled residual. One block per row.
// All f32 reads happen before the reduction barriers; half writes after.
// Wd in {256, 512}.
// ---------------------------------------------------------------------------
__global__ __launch_bounds__(256)
void ln_gelu_split(float* __restrict__ buf, const float* __restrict__ g,
                   const float* __restrict__ be, int Wd)
{
  __shared__ float rs[4], rs2[4];
  const int row = blockIdx.x;
  const int tid = threadIdx.x;
  float* x = buf + (size_t)row * Wd;
  const float v0 = x[tid];
  const float v1 = (Wd > 256) ? x[tid + 256] : 0.f;
  float s = v0 + v1, s2 = v0 * v0 + v1 * v1;
  #pragma unroll
  for (int m = 32; m; m >>= 1) { s += __shfl_down(s, m); s2 += __shfl_down(s2, m); }
  const int ln = tid & 63, wv = tid >> 6;
  if (ln == 0) { rs[wv] = s; rs2[wv] = s2; }
  __syncthreads();
  if (tid == 0) {
    const float S = rs[0] + rs[1] + rs[2] + rs[3];
    const float S2 = rs2[0] + rs2[1] + rs2[2] + rs2[3];
    const float mean = S / Wd;
    const float var = S2 / Wd - mean * mean;
    rs[0] = mean; rs2[0] = 1.0f / sqrtf(var + 1e-5f);
  }
  __syncthreads();
  const float mean = rs[0], inv = rs2[0];
  float y0 = (v0 - mean) * inv * g[tid] + be[tid];
  y0 = 0.5f * y0 * (1.f + erff(y0 * 0.70710678118654752f));
  float y1 = 0.f;
  if (Wd > 256) {
    y1 = (v1 - mean) * inv * g[tid + 256] + be[tid + 256];
    y1 = 0.5f * y1 * (1.f + erff(y1 * 0.70710678118654752f));
  }
  _Float16* hb = reinterpret_cast<_Float16*>(x);
  const Split s0 = split2(y0);
  hb[tid] = s0.h; hb[Wd + tid] = s0.m;
  if (Wd > 256) {
    const Split s1 = split2(y1);
    hb[tid + 256] = s1.h; hb[Wd + tid + 256] = s1.m;
  }
}

// ---------------------------------------------------------------------------
// VQ argmin via fp16-split MFMA (unchanged from round 6, which passed).
// Block = 64 rows x 1024 codes (grid 4 x 512).
// ---------------------------------------------------------------------------
__global__ __launch_bounds__(256)
void vq_mfma(const float* __restrict__ Z, const _Float16* __restrict__ E1,
             const _Float16* __restrict__ E2, const float* __restrict__ e2,
             float* __restrict__ pval, int* __restrict__ pidx)
{
  __shared__ _Float16 Zs1[64 * 136];
  __shared__ _Float16 Zs2[64 * 136];
  __shared__ _Float16 Es1[128 * 40];
  __shared__ _Float16 Es2[128 * 40];

  const int tid  = threadIdx.x;
  const int lane = tid & 63;
  const int wid  = tid >> 6;
  const int l15  = lane & 15;
  const int lg   = lane >> 4;
  const int wn   = wid * 32;
  const int m0   = blockIdx.y * 64;
  const int split = blockIdx.x;

  {
    const int zr = tid >> 2;
    #pragma unroll
    for (int q = 0; q < 8; ++q) {
      const int kk = ((tid & 3) << 2) + (q << 4);
      float4 v = *reinterpret_cast<const float4*>(Z + (size_t)(m0 + zr) * 128 + kk);
      const Split sx = split2(v.x), sy = split2(v.y), sz = split2(v.z), sw = split2(v.w);
      f16x4 h, m;
      h[0] = sx.h; h[1] = sy.h; h[2] = sz.h; h[3] = sw.h;
      m[0] = sx.m; m[1] = sy.m; m[2] = sz.m; m[3] = sw.m;
      *reinterpret_cast<f16x4*>(&Zs1[zr * 136 + kk]) = h;
      *reinterpret_cast<f16x4*>(&Zs2[zr * 136 + kk]) = m;
    }
  }

  float bv[16];
  int   bi[16];
  #pragma unroll
  for (int s = 0; s < 16; ++s) { bv[s] = 3.4e38f; bi[s] = 0x7fffffff; }

  const int sbn = tid >> 1;
  const int sbk = (tid & 1) << 4;

  #pragma unroll 1
  for (int ch = 0; ch < 8; ++ch) {
    const int n0 = split * 1024 + ch * 128;
    f32x4 hi[4][2], mid[4][2];
    #pragma unroll
    for (int i = 0; i < 4; ++i)
      #pragma unroll
      for (int j = 0; j < 2; ++j) { hi[i][j] = (f32x4)0.f; mid[i][j] = (f32x4)0.f; }

    #pragma unroll 1
    for (int kt = 0; kt < 4; ++kt) {
      const int k0 = kt << 5;
      {
        const size_t gb = (size_t)(n0 + sbn) * 128 + k0 + sbk;
        const int lb = sbn * 40 + sbk;
        *reinterpret_cast<uint4*>(&Es1[lb])     = *reinterpret_cast<const uint4*>(E1 + gb);
        *reinterpret_cast<uint4*>(&Es1[lb + 8]) = *reinterpret_cast<const uint4*>(E1 + gb + 8);
        *reinterpret_cast<uint4*>(&Es2[lb])     = *reinterpret_cast<const uint4*>(E2 + gb);
        *reinterpret_cast<uint4*>(&Es2[lb + 8]) = *reinterpret_cast<const uint4*>(E2 + gb + 8);
      }
      __syncthreads();

      f16x8 a[4], b[2], b2[2];
      #pragma unroll
      for (int i = 0; i < 4; ++i)
        a[i] = *reinterpret_cast<const f16x8*>(&Zs1[(i * 16 + l15) * 136 + k0 + 8 * lg]);
      #pragma unroll
      for (int j = 0; j < 2; ++j)
        b[j] = *reinterpret_cast<const f16x8*>(&Es1[(wn + j * 16 + l15) * 40 + 8 * lg]);
      #pragma unroll
      for (int i = 0; i < 4; ++i)
        #pragma unroll
        for (int j = 0; j < 2; ++j)
          hi[i][j] = __builtin_amdgcn_mfma_f32_16x16x32_f16(a[i], b[j], hi[i][j], 0, 0, 0);
      #pragma unroll
      for (int j = 0; j < 2; ++j)
        b2[j] = *reinterpret_cast<const f16x8*>(&Es2[(wn + j * 16 + l15) * 40 + 8 * lg]);
      #pragma unroll
      for (int i = 0; i < 4; ++i)
        #pragma unroll
        for (int j = 0; j < 2; ++j)
          mid[i][j] = __builtin_amdgcn_mfma_f32_16x16x32_f16(a[i], b2[j], mid[i][j], 0, 0, 0);
      #pragma unroll
      for (int i = 0; i < 4; ++i)
        a[i] = *reinterpret_cast<const f16x8*>(&Zs2[(i * 16 + l15) * 136 + k0 + 8 * lg]);
      #pragma unroll
      for (int i = 0; i < 4; ++i)
        #pragma unroll
        for (int j = 0; j < 2; ++j)
          mid[i][j] = __builtin_amdgcn_mfma_f32_16x16x32_f16(a[i], b[j], mid[i][j], 0, 0, 0);
      __syncthreads();
    }

    #pragma unroll
    for (int j = 0; j < 2; ++j) {
      const int c = n0 + wn + j * 16 + l15;
      const float ec = e2[c];
      #pragma unroll
      for (int i = 0; i < 4; ++i)
        #pragma unroll
        for (int r = 0; r < 4; ++r) {
          const float sc = ec - 2.f * (hi[i][j][r] + 0.00390625f * mid[i][j][r]);
          if (sc < bv[i * 4 + r]) { bv[i * 4 + r] = sc; bi[i * 4 + r] = c; }
        }
    }
  }

  #pragma unroll
  for (int s = 0; s < 16; ++s) {
    float v = bv[s]; int ix = bi[s];
    #pragma unroll
    for (int m = 1; m < 16; m <<= 1) {
      const float ov = __shfl_xor(v, m);
      const int   oi = __shfl_xor(ix, m);
      if (ov < v || (ov == v && oi < ix)) { v = ov; ix = oi; }
    }
    if (l15 == 0) {
      const int row = m0 + (s >> 2) * 16 + 4 * lg + (s & 3);
      pval[(size_t)row * 16 + split * 4 + wid] = v;
      pidx[(size_t)row * 16 + split * 4 + wid] = ix;
    }
  }
}

// weight prep: W [K][N] f32 -> Bh/Bm [N][Kp] fp16 (transposed, zero-padded)
__global__ void prep_wT(const float* __restrict__ W, _Float16* __restrict__ Bh,
                        _Float16* __restrict__ Bm, int K, int N, int nshift,
                        int nmask, int Kp)
{
  const int i = blockIdx.x * 256 + threadIdx.x;
  if (i >= N * Kp) return;
  const int n = i & nmask;
  const int k = i >> nshift;
  const float v = (k < K) ? W[(size_t)k * N + n] : 0.f;
  const Split s = split2(v);
  Bh[(size_t)n * Kp + k] = s.h;
  Bm[(size_t)n * Kp + k] = s.m;
}

__global__ void prep_emb(const float* __restrict__ E, _Float16* __restrict__ E1,
                         _Float16* __restrict__ E2)
{
  const int i = blockIdx.x * 256 + threadIdx.x;
  const Split s = split2(E[i]);
  E1[i] = s.h; E2[i] = s.m;
}

__global__ void vq_reduce(const float* __restrict__ pval, const int* __restrict__ pidx,
                          int* __restrict__ idxout, float* __restrict__ idxf,
                          int* __restrict__ counts)
{
  const int b = blockIdx.x * 256 + threadIdx.x;
  if (b >= B_ROWS) return;
  float best = 3.4e38f; int bix = 0x7fffffff;
  #pragma unroll
  for (int j = 0; j < 16; ++j) {
    const float v = pval[(size_t)b * 16 + j];
    const int   ii = pidx[(size_t)b * 16 + j];
    if (v < best || (v == best && ii < bix)) { best = v; bix = ii; }
  }
  idxout[b] = bix;
  idxf[b] = (float)bix;
  atomicAdd(&counts[bix], 1);
}

__global__ __launch_bounds__(256)
void gather_commit(const int* __restrict__ idx, const float* __restrict__ E,
                   const float* __restrict__ ZE, float* __restrict__ ZQ,
                   float* __restrict__ cpart)
{
  __shared__ float red[4];
  const int b = blockIdx.x * 8 + (threadIdx.x >> 5);
  const int ch = threadIdx.x & 31;
  const int k = idx[b];
  float4 q = *reinterpret_cast<const float4*>(E + (size_t)k * 128 + ch * 4);
  float4 z = *reinterpret_cast<const float4*>(ZE + (size_t)b * 128 + ch * 4);
  *reinterpret_cast<float4*>(ZQ + (size_t)b * 128 + ch * 4) = q;
  float dx = q.x - z.x, dy = q.y - z.y, dz = q.z - z.z, dw = q.w - z.w;
  float s = dx * dx + dy * dy + dz * dz + dw * dw;
  #pragma unroll
  for (int m = 32; m; m >>= 1) s += __shfl_down(s, m);
  const int lane = threadIdx.x & 63, wv = threadIdx.x >> 6;
  if (lane == 0) red[wv] = s;
  __syncthreads();
  if (threadIdx.x == 0) cpart[blockIdx.x] = red[0] + red[1] + red[2] + red[3];
}

__global__ void e2_kernel(const float* __restrict__ E, float* __restrict__ e2)
{
  const int k = blockIdx.x * 256 + threadIdx.x;
  if (k >= KCODES) return;
  float s = 0.f;
  #pragma unroll 4
  for (int d = 0; d < 128; ++d) { float v = E[(size_t)k * 128 + d]; s += v * v; }
  e2[k] = s;
}

__global__ void zero_counts(int* counts)
{
  const int i = blockIdx.x * 256 + threadIdx.x;
  if (i < KCODES) counts[i] = 0;
}

__global__ void gelu_ew(float* __restrict__ p, int n)
{
  const int i = blockIdx.x * 256 + threadIdx.x;
  if (i < n) { float v = p[i]; p[i] = 0.5f * v * (1.f + erff(v * 0.70710678118654752f)); }
}

__global__ void gemm_n2(const float* __restrict__ T, const float* __restrict__ W6,
                        const float* __restrict__ b6, float* __restrict__ V, int M)
{
  const int r = blockIdx.x * 256 + threadIdx.x;
  if (r >= M) return;
  float a0 = b6[0], a1 = b6[1];
  #pragma unroll 4
  for (int d = 0; d < 128; ++d) {
    float t = T[(size_t)r * 128 + d];
    a0 = fmaf(t, W6[d * 2 + 0], a0);
    a1 = fmaf(t, W6[d * 2 + 1], a1);
  }
  V[r * 2 + 0] = a0; V[r * 2 + 1] = a1;
}

__global__ void vel_gather(const int* __restrict__ idx, const float* __restrict__ V,
                           float* __restrict__ out)
{
  const int b = blockIdx.x * 256 + threadIdx.x;
  if (b >= B_ROWS) return;
  const int k = idx[b];
  out[b * 2 + 0] = V[k * 2 + 0];
  out[b * 2 + 1] = V[k * 2 + 1];
}

__global__ __launch_bounds__(256)
void stats_kernel(const float* __restrict__ cpart, const int* __restrict__ counts,
                  float* __restrict__ outs)
{
  __shared__ float sh[256];
  __shared__ float sh2[256];
  __shared__ int shi[256];
  const int t = threadIdx.x;
  float cs = 0.f;
  for (int i = t; i < 4096; i += 256) cs += cpart[i];
  float h = 0.f; int act = 0;
  for (int k = t; k < KCODES; k += 256) {
    float avg = counts[k] * (1.0f / 32768.0f);
    h += avg * logf(avg + 1e-10f);
    act += (avg > 0.001f) ? 1 : 0;
  }
  sh[t] = cs; sh2[t] = h; shi[t] = act;
  __syncthreads();
  for (int s = 128; s; s >>= 1) {
    if (t < s) { sh[t] += sh[t + s]; sh2[t] += sh2[t + s]; shi[t] += shi[t + s]; }
    __syncthreads();
  }
  if (t == 0) {
    outs[0] = 0.25f * sh[0] / (32768.0f * 128.0f);
    outs[1] = expf(-sh2[0]);
    outs[2] = (float)shi[0];
  }
}

extern "C" void kernel_launch(void* const* d_in, const int* in_sizes, int n_in,
                              void* d_out, int out_size, void* d_ws, size_t ws_size,
                              hipStream_t stream)
{
  const float* x   = (const float*)d_in[0];
  const float* W1  = (const float*)d_in[1];
  const float* b1  = (const float*)d_in[2];
  const float* g1  = (const float*)d_in[3];
  const float* be1 = (const float*)d_in[4];
  const float* W2  = (const float*)d_in[5];
  const float* b2  = (const float*)d_in[6];
  const float* g2  = (const float*)d_in[7];
  const float* be2 = (const float*)d_in[8];
  const float* W3  = (const float*)d_in[9];
  const float* b3  = (const float*)d_in[10];
  const float* emb = (const float*)d_in[11];
  const float* W4  = (const float*)d_in[12];
  const float* b4  = (const float*)d_in[13];
  const float* g3  = (const float*)d_in[14];
  const float* be3 = (const float*)d_in[15];
  const float* W5  = (const float*)d_in[16];
  const float* b5  = (const float*)d_in[17];
  const float* W6  = (const float*)d_in[18];
  const float* b6  = (const float*)d_in[19];

  float* out = (float*)d_out;
  float* o_vel  = out;                                   // [B,2]
  float* o_ze   = out + 65536;                           // [B,128]
  float* o_zq   = out + 65536 + B_ROWS * 128;            // [B,128]
  float* o_idx  = out + 65536 + 2 * B_ROWS * 128;        // [B] (as float)
  float* o_scal = o_idx + B_ROWS;                        // 3 scalars

  float* ws = (float*)d_ws;
  // region A [0 .. 16.78M): h1f during encoder; after GEMM2 it is dead ->
  // reused for VQ partials + decoder buffers.
  float* h1f   = ws;                        // [B,512] f32 -> in-place split halves
  float* pval  = ws;                        // [B,16]
  int*   pidx  = (int*)(ws + 524288);       // [B,16]
  float* t1f   = ws + 1048576;              // [4096,256] f32 -> in-place split
  float* t2    = ws + 2097152;              // [4096,128]
  float* vv    = ws + 2621440;              // [4096,2]
  // region B: h2f
  float* h2f   = ws + 16777216;             // [B,256] f32 -> in-place split
  // region C: small
  float* e2    = ws + 25165824;             // [4096]
  int*   ind   = (int*)(ws + 25169920);     // [B]
  int*   cnt   = (int*)(ws + 25202688);     // [4096]
  float* cpart = ws + 25206784;             // [4096]
  // region D: fp16 weights (byte offset 100,843,520; 16B aligned)
  _Float16* hb  = (_Float16*)(ws + 25210880);
  _Float16* E1  = hb;                       // 4096*128
  _Float16* E2  = E1 + 524288;
  _Float16* W1a = E2 + 524288;              // [512][1440]
  _Float16* W1b = W1a + 737280;
  _Float16* W2a = W1b + 737280;             // [256][512]
  _Float16* W2b = W2a + 131072;
  _Float16* W3a = W2b + 131072;             // [128][256]
  _Float16* W3b = W3a + 32768;
  _Float16* W4a = W3b + 32768;              // [256][128]
  _Float16* W4b = W4a + 32768;
  _Float16* W5a = W4b + 32768;              // [128][256]
  _Float16* W5b = W5a + 32768;
  // total ~106.8 MB (same budget as round 6)

  // 1. init + weight prep
  zero_counts<<<16, 256, 0, stream>>>(cnt);
  e2_kernel<<<16, 256, 0, stream>>>(emb, e2);
  prep_emb<<<2048, 256, 0, stream>>>(emb, E1, E2);
  prep_wT<<<2880, 256, 0, stream>>>(W1, W1a, W1b, 1420, 512, 9, 511, 1440);
  prep_wT<<<512, 256, 0, stream>>>(W2, W2a, W2b, 512, 256, 8, 255, 512);
  prep_wT<<<128, 256, 0, stream>>>(W3, W3a, W3b, 256, 128, 7, 127, 256);
  prep_wT<<<128, 256, 0, stream>>>(W4, W4a, W4b, 128, 256, 8, 255, 128);
  prep_wT<<<128, 256, 0, stream>>>(W5, W5a, W5b, 256, 128, 7, 127, 256);

  // 2. encoder
  hgemm<true><<<dim3(8, 256), 256, 0, stream>>>(x, nullptr, nullptr, 0,
      W1a, W1b, b1, h1f, B_ROWS, 512, 1420, 1440);
  ln_gelu_split<<<B_ROWS, 256, 0, stream>>>(h1f, g1, be1, 512);
  hgemm<false><<<dim3(4, 256), 256, 0, stream>>>(nullptr,
      (const _Float16*)h1f, (const _Float16*)h1f + 512, 1024,
      W2a, W2b, b2, h2f, B_ROWS, 256, 512, 512);
  ln_gelu_split<<<B_ROWS, 256, 0, stream>>>(h2f, g2, be2, 256);
  hgemm<false><<<dim3(2, 256), 256, 0, stream>>>(nullptr,
      (const _Float16*)h2f, (const _Float16*)h2f + 256, 512,
      W3a, W3b, b3, o_ze, B_ROWS, 128, 256, 256);

  // 3. VQ
  vq_mfma<<<dim3(4, 512), 256, 0, stream>>>(o_ze, E1, E2, e2, pval, pidx);
  vq_reduce<<<128, 256, 0, stream>>>(pval, pidx, ind, o_idx, cnt);
  gather_commit<<<4096, 256, 0, stream>>>(ind, emb, o_ze, o_zq, cpart);

  // 4. decoder on the 4096 distinct codes, then gather
  hgemm<false><<<dim3(4, 32), 256, 0, stream>>>(nullptr, E1, E2, 128,
      W4a, W4b, b4, t1f, KCODES, 256, 128, 128);
  ln_gelu_split<<<KCODES, 256, 0, stream>>>(t1f, g3, be3, 256);
  hgemm<false><<<dim3(2, 32), 256, 0, stream>>>(nullptr,
      (const _Float16*)t1f, (const _Float16*)t1f + 256, 512,
      W5a, W5b, b5, t2, KCODES, 128, 256, 256);
  gelu_ew<<<(KCODES * 128 + 255) / 256, 256, 0, stream>>>(t2, KCODES * 128);
  gemm_n2<<<(KCODES + 255) / 256, 256, 0, stream>>>(t2, W6, b6, vv, KCODES);
  vel_gather<<<128, 256, 0, stream>>>(ind, vv, o_vel);

  // 5. scalars
  stats_kernel<<<1, 256, 0, stream>>>(cpart, cnt, o_scal);
}

// Round 8
// 788.873 us; speedup vs baseline: 2.4250x; 1.3484x over previous
//
#include <hip/hip_runtime.h>

#define B_ROWS 32768
#define KCODES 4096

typedef float f32x4 __attribute__((ext_vector_type(4)));
typedef _Float16 f16x8 __attribute__((ext_vector_type(8)));
typedef _Float16 f16x4 __attribute__((ext_vector_type(4)));

struct Split { _Float16 h, m; };

// split f32 -> fp16 head + fp16 scaled residual (residual x256 stays normal;
// C = hi + mid/256 recombines to f32-grade accuracy)
__device__ __forceinline__ Split split2(float v)
{
  Split s;
  s.h = (_Float16)v;
  s.m = (_Float16)((v - (float)s.h) * 256.f);
  return s;
}

// ---------------------------------------------------------------------------
// fp16-split MFMA GEMM. Block tile 128x64, 4 waves of 64x32. BK=32.
// 1-D grid with XCD-L2 swizzle: flat -> xcd=flat&7, s=flat>>3, nb=s%nbx,
// mb=(s/nbx)*8+xcd. All n-blocks of an m-tile share one XCD (flat%8==mb%8)
// and are dispatched within one 8*nbx window -> A k-chunks L2-hit instead of
// re-fetching from HBM (round-7 FETCH was 5.6x ideal). Requires mblocks%8==0.
// SPLITA=true : A f32 [M][K], split during staging (K-tail guarded).
// SPLITA=false: A pre-split fp16 pair, row stride Astr halves.
// hi += A1B1 ; mid += A1*B2s + A2s*B1 ; C = hi + mid*2^-8 + bias.
// LDS stride 40 halves; all LDS writes 16B-wide (2-way banks max).
// ---------------------------------------------------------------------------
template<bool SPLITA>
__global__ __launch_bounds__(256, 3)
void hgemm(const float* __restrict__ Af, const _Float16* __restrict__ Ah,
           const _Float16* __restrict__ Am, int Astr,
           const _Float16* __restrict__ Bh, const _Float16* __restrict__ Bm,
           const float* __restrict__ bias, float* __restrict__ C,
           int M, int N, int K, int Kp, int nbx)
{
  __shared__ _Float16 As1[128 * 40];
  __shared__ _Float16 As2[128 * 40];
  __shared__ _Float16 Bs1[64 * 40];
  __shared__ _Float16 Bs2[64 * 40];

  const int flat = blockIdx.x;
  const int s_   = flat >> 3;
  const int mb   = (s_ / nbx) * 8 + (flat & 7);
  const int nb   = s_ % nbx;
  const int m0   = mb * 128;
  const int n0   = nb * 64;

  const int tid  = threadIdx.x;
  const int lane = tid & 63;
  const int wid  = tid >> 6;
  const int l15  = lane & 15;
  const int lg   = lane >> 4;
  const int wm   = (wid >> 1) * 64;
  const int wn   = (wid & 1) * 32;

  f32x4 hi[4][2], mid[4][2];
  #pragma unroll
  for (int i = 0; i < 4; ++i)
    #pragma unroll
    for (int j = 0; j < 2; ++j) { hi[i][j] = (f32x4)0.f; mid[i][j] = (f32x4)0.f; }

  const int sar = tid >> 1;           // pre-split A: 0..127
  const int sak = (tid & 1) << 4;     // 0/16 halves
  const int far = tid >> 2;           // f32 A: row 0..63 (+64)
  const int fak = (tid & 3) << 3;     // 0,8,16,24 halves
  const int sbn = tid >> 2;           // 0..63
  const int sbk = (tid & 3) << 3;     // 0,8,16,24 halves

  const int nk = Kp >> 5;
  #pragma unroll 1
  for (int kt = 0; kt < nk; ++kt) {
    const int k0 = kt << 5;
    // ---- stage A 128x32 (16B writes) ----
    if (SPLITA) {
      #pragma unroll
      for (int p = 0; p < 2; ++p) {
        const int r = far + (p << 6);
        const int c = k0 + fak;
        const float* src = Af + (size_t)(m0 + r) * K + c;
        float4 v0 = make_float4(0.f, 0.f, 0.f, 0.f), v1 = v0;
        if (c < K)     v0 = *reinterpret_cast<const float4*>(src);      // K%4==0
        if (c + 4 < K) v1 = *reinterpret_cast<const float4*>(src + 4);
        const Split s0 = split2(v0.x), s1 = split2(v0.y), s2 = split2(v0.z), s3 = split2(v0.w);
        const Split s4 = split2(v1.x), s5 = split2(v1.y), s6 = split2(v1.z), s7 = split2(v1.w);
        f16x8 h, m;
        h[0]=s0.h; h[1]=s1.h; h[2]=s2.h; h[3]=s3.h; h[4]=s4.h; h[5]=s5.h; h[6]=s6.h; h[7]=s7.h;
        m[0]=s0.m; m[1]=s1.m; m[2]=s2.m; m[3]=s3.m; m[4]=s4.m; m[5]=s5.m; m[6]=s6.m; m[7]=s7.m;
        *reinterpret_cast<f16x8*>(&As1[r * 40 + fak]) = h;
        *reinterpret_cast<f16x8*>(&As2[r * 40 + fak]) = m;
      }
    } else {
      const size_t gA = (size_t)(m0 + sar) * Astr + k0 + sak;
      const int lA = sar * 40 + sak;
      *reinterpret_cast<uint4*>(&As1[lA])     = *reinterpret_cast<const uint4*>(Ah + gA);
      *reinterpret_cast<uint4*>(&As1[lA + 8]) = *reinterpret_cast<const uint4*>(Ah + gA + 8);
      *reinterpret_cast<uint4*>(&As2[lA])     = *reinterpret_cast<const uint4*>(Am + gA);
      *reinterpret_cast<uint4*>(&As2[lA + 8]) = *reinterpret_cast<const uint4*>(Am + gA + 8);
    }
    // ---- stage B 64x32 ----
    {
      const size_t gB = (size_t)(n0 + sbn) * Kp + k0 + sbk;
      const int lB = sbn * 40 + sbk;
      *reinterpret_cast<uint4*>(&Bs1[lB]) = *reinterpret_cast<const uint4*>(Bh + gB);
      *reinterpret_cast<uint4*>(&Bs2[lB]) = *reinterpret_cast<const uint4*>(Bm + gB);
    }
    __syncthreads();

    f16x8 a1[4], b[2];
    #pragma unroll
    for (int i = 0; i < 4; ++i)
      a1[i] = *reinterpret_cast<const f16x8*>(&As1[(wm + i * 16 + l15) * 40 + 8 * lg]);
    #pragma unroll
    for (int j = 0; j < 2; ++j)
      b[j] = *reinterpret_cast<const f16x8*>(&Bs1[(wn + j * 16 + l15) * 40 + 8 * lg]);
    #pragma unroll
    for (int i = 0; i < 4; ++i)
      #pragma unroll
      for (int j = 0; j < 2; ++j)
        hi[i][j] = __builtin_amdgcn_mfma_f32_16x16x32_f16(a1[i], b[j], hi[i][j], 0, 0, 0);
    #pragma unroll
    for (int i = 0; i < 4; ++i) {
      const f16x8 a2 = *reinterpret_cast<const f16x8*>(&As2[(wm + i * 16 + l15) * 40 + 8 * lg]);
      #pragma unroll
      for (int j = 0; j < 2; ++j)
        mid[i][j] = __builtin_amdgcn_mfma_f32_16x16x32_f16(a2, b[j], mid[i][j], 0, 0, 0);
    }
    #pragma unroll
    for (int j = 0; j < 2; ++j)
      b[j] = *reinterpret_cast<const f16x8*>(&Bs2[(wn + j * 16 + l15) * 40 + 8 * lg]);
    #pragma unroll
    for (int i = 0; i < 4; ++i)
      #pragma unroll
      for (int j = 0; j < 2; ++j)
        mid[i][j] = __builtin_amdgcn_mfma_f32_16x16x32_f16(a1[i], b[j], mid[i][j], 0, 0, 0);
    __syncthreads();
  }

  // epilogue: D row = 4*lg + r, col = l15 (m89-verified layout)
  #pragma unroll
  for (int i = 0; i < 4; ++i)
    #pragma unroll
    for (int j = 0; j < 2; ++j) {
      const int col = n0 + wn + j * 16 + l15;
      const float bs = bias[col];
      #pragma unroll
      for (int r = 0; r < 4; ++r) {
        const int row = m0 + wm + i * 16 + 4 * lg + r;
        C[(size_t)row * N + col] = hi[i][j][r] + 0.00390625f * mid[i][j][r] + bs;
      }
    }
}

// ---------------------------------------------------------------------------
// Row LayerNorm + exact GELU, writing split fp16 pair IN-PLACE over the f32
// row: halves [0..Wd) = head, [Wd..2Wd) = scaled residual. One block per row.
// ---------------------------------------------------------------------------
__global__ __launch_bounds__(256)
void ln_gelu_split(float* __restrict__ buf, const float* __restrict__ g,
                   const float* __restrict__ be, int Wd)
{
  __shared__ float rs[4], rs2[4];
  const int row = blockIdx.x;
  const int tid = threadIdx.x;
  float* x = buf + (size_t)row * Wd;
  const float v0 = x[tid];
  const float v1 = (Wd > 256) ? x[tid + 256] : 0.f;
  float s = v0 + v1, s2 = v0 * v0 + v1 * v1;
  #pragma unroll
  for (int m = 32; m; m >>= 1) { s += __shfl_down(s, m); s2 += __shfl_down(s2, m); }
  const int ln = tid & 63, wv = tid >> 6;
  if (ln == 0) { rs[wv] = s; rs2[wv] = s2; }
  __syncthreads();
  if (tid == 0) {
    const float S = rs[0] + rs[1] + rs[2] + rs[3];
    const float S2 = rs2[0] + rs2[1] + rs2[2] + rs2[3];
    const float mean = S / Wd;
    const float var = S2 / Wd - mean * mean;
    rs[0] = mean; rs2[0] = 1.0f / sqrtf(var + 1e-5f);
  }
  __syncthreads();
  const float mean = rs[0], inv = rs2[0];
  float y0 = (v0 - mean) * inv * g[tid] + be[tid];
  y0 = 0.5f * y0 * (1.f + erff(y0 * 0.70710678118654752f));
  float y1 = 0.f;
  if (Wd > 256) {
    y1 = (v1 - mean) * inv * g[tid + 256] + be[tid + 256];
    y1 = 0.5f * y1 * (1.f + erff(y1 * 0.70710678118654752f));
  }
  _Float16* hb = reinterpret_cast<_Float16*>(x);
  const Split s0 = split2(y0);
  hb[tid] = s0.h; hb[Wd + tid] = s0.m;
  if (Wd > 256) {
    const Split s1 = split2(y1);
    hb[tid + 256] = s1.h; hb[Wd + tid + 256] = s1.m;
  }
}

// ---------------------------------------------------------------------------
// VQ argmin via fp16-split MFMA. 1-D grid of 2048 with the same XCD swizzle
// (4 splits of one 64-row tile share an XCD). Block = 64 rows x 1024 codes.
// ---------------------------------------------------------------------------
__global__ __launch_bounds__(256)
void vq_mfma(const float* __restrict__ Z, const _Float16* __restrict__ E1,
             const _Float16* __restrict__ E2, const float* __restrict__ e2,
             float* __restrict__ pval, int* __restrict__ pidx)
{
  __shared__ _Float16 Zs1[64 * 136];
  __shared__ _Float16 Zs2[64 * 136];
  __shared__ _Float16 Es1[128 * 40];
  __shared__ _Float16 Es2[128 * 40];

  const int flat = blockIdx.x;
  const int s_   = flat >> 3;
  const int mb   = (s_ >> 2) * 8 + (flat & 7);
  const int split = s_ & 3;
  const int m0   = mb * 64;

  const int tid  = threadIdx.x;
  const int lane = tid & 63;
  const int wid  = tid >> 6;
  const int l15  = lane & 15;
  const int lg   = lane >> 4;
  const int wn   = wid * 32;

  {
    const int zr = tid >> 2;
    #pragma unroll
    for (int q = 0; q < 8; ++q) {
      const int kk = ((tid & 3) << 2) + (q << 4);
      float4 v = *reinterpret_cast<const float4*>(Z + (size_t)(m0 + zr) * 128 + kk);
      const Split sx = split2(v.x), sy = split2(v.y), sz = split2(v.z), sw = split2(v.w);
      f16x4 h, m;
      h[0] = sx.h; h[1] = sy.h; h[2] = sz.h; h[3] = sw.h;
      m[0] = sx.m; m[1] = sy.m; m[2] = sz.m; m[3] = sw.m;
      *reinterpret_cast<f16x4*>(&Zs1[zr * 136 + kk]) = h;
      *reinterpret_cast<f16x4*>(&Zs2[zr * 136 + kk]) = m;
    }
  }

  float bv[16];
  int   bi[16];
  #pragma unroll
  for (int s = 0; s < 16; ++s) { bv[s] = 3.4e38f; bi[s] = 0x7fffffff; }

  const int sbn = tid >> 1;
  const int sbk = (tid & 1) << 4;

  #pragma unroll 1
  for (int ch = 0; ch < 8; ++ch) {
    const int n0 = split * 1024 + ch * 128;
    f32x4 hi[4][2], mid[4][2];
    #pragma unroll
    for (int i = 0; i < 4; ++i)
      #pragma unroll
      for (int j = 0; j < 2; ++j) { hi[i][j] = (f32x4)0.f; mid[i][j] = (f32x4)0.f; }

    #pragma unroll 1
    for (int kt = 0; kt < 4; ++kt) {
      const int k0 = kt << 5;
      {
        const size_t gb = (size_t)(n0 + sbn) * 128 + k0 + sbk;
        const int lb = sbn * 40 + sbk;
        *reinterpret_cast<uint4*>(&Es1[lb])     = *reinterpret_cast<const uint4*>(E1 + gb);
        *reinterpret_cast<uint4*>(&Es1[lb + 8]) = *reinterpret_cast<const uint4*>(E1 + gb + 8);
        *reinterpret_cast<uint4*>(&Es2[lb])     = *reinterpret_cast<const uint4*>(E2 + gb);
        *reinterpret_cast<uint4*>(&Es2[lb + 8]) = *reinterpret_cast<const uint4*>(E2 + gb + 8);
      }
      __syncthreads();

      f16x8 a[4], b[2], b2[2];
      #pragma unroll
      for (int i = 0; i < 4; ++i)
        a[i] = *reinterpret_cast<const f16x8*>(&Zs1[(i * 16 + l15) * 136 + k0 + 8 * lg]);
      #pragma unroll
      for (int j = 0; j < 2; ++j)
        b[j] = *reinterpret_cast<const f16x8*>(&Es1[(wn + j * 16 + l15) * 40 + 8 * lg]);
      #pragma unroll
      for (int i = 0; i < 4; ++i)
        #pragma unroll
        for (int j = 0; j < 2; ++j)
          hi[i][j] = __builtin_amdgcn_mfma_f32_16x16x32_f16(a[i], b[j], hi[i][j], 0, 0, 0);
      #pragma unroll
      for (int j = 0; j < 2; ++j)
        b2[j] = *reinterpret_cast<const f16x8*>(&Es2[(wn + j * 16 + l15) * 40 + 8 * lg]);
      #pragma unroll
      for (int i = 0; i < 4; ++i)
        #pragma unroll
        for (int j = 0; j < 2; ++j)
          mid[i][j] = __builtin_amdgcn_mfma_f32_16x16x32_f16(a[i], b2[j], mid[i][j], 0, 0, 0);
      #pragma unroll
      for (int i = 0; i < 4; ++i)
        a[i] = *reinterpret_cast<const f16x8*>(&Zs2[(i * 16 + l15) * 136 + k0 + 8 * lg]);
      #pragma unroll
      for (int i = 0; i < 4; ++i)
        #pragma unroll
        for (int j = 0; j < 2; ++j)
          mid[i][j] = __builtin_amdgcn_mfma_f32_16x16x32_f16(a[i], b[j], mid[i][j], 0, 0, 0);
      __syncthreads();
    }

    #pragma unroll
    for (int j = 0; j < 2; ++j) {
      const int c = n0 + wn + j * 16 + l15;
      const float ec = e2[c];
      #pragma unroll
      for (int i = 0; i < 4; ++i)
        #pragma unroll
        for (int r = 0; r < 4; ++r) {
          const float sc = ec - 2.f * (hi[i][j][r] + 0.00390625f * mid[i][j][r]);
          if (sc < bv[i * 4 + r]) { bv[i * 4 + r] = sc; bi[i * 4 + r] = c; }
        }
    }
  }

  #pragma unroll
  for (int s = 0; s < 16; ++s) {
    float v = bv[s]; int ix = bi[s];
    #pragma unroll
    for (int m = 1; m < 16; m <<= 1) {
      const float ov = __shfl_xor(v, m);
      const int   oi = __shfl_xor(ix, m);
      if (ov < v || (ov == v && oi < ix)) { v = ov; ix = oi; }
    }
    if (l15 == 0) {
      const int row = m0 + (s >> 2) * 16 + 4 * lg + (s & 3);
      pval[(size_t)row * 16 + split * 4 + wid] = v;
      pidx[(size_t)row * 16 + split * 4 + wid] = ix;
    }
  }
}

// weight prep: W [K][N] f32 -> Bh/Bm [N][Kp] fp16 (transposed, zero-padded)
__global__ void prep_wT(const float* __restrict__ W, _Float16* __restrict__ Bh,
                        _Float16* __restrict__ Bm, int K, int N, int nshift,
                        int nmask, int Kp)
{
  const int i = blockIdx.x * 256 + threadIdx.x;
  if (i >= N * Kp) return;
  const int n = i & nmask;
  const int k = i >> nshift;
  const float v = (k < K) ? W[(size_t)k * N + n] : 0.f;
  const Split s = split2(v);
  Bh[(size_t)n * Kp + k] = s.h;
  Bm[(size_t)n * Kp + k] = s.m;
}

__global__ void prep_emb(const float* __restrict__ E, _Float16* __restrict__ E1,
                         _Float16* __restrict__ E2)
{
  const int i = blockIdx.x * 256 + threadIdx.x;
  const Split s = split2(E[i]);
  E1[i] = s.h; E2[i] = s.m;
}

__global__ void vq_reduce(const float* __restrict__ pval, const int* __restrict__ pidx,
                          int* __restrict__ idxout, float* __restrict__ idxf,
                          int* __restrict__ counts)
{
  const int b = blockIdx.x * 256 + threadIdx.x;
  if (b >= B_ROWS) return;
  float best = 3.4e38f; int bix = 0x7fffffff;
  #pragma unroll
  for (int j = 0; j < 16; ++j) {
    const float v = pval[(size_t)b * 16 + j];
    const int   ii = pidx[(size_t)b * 16 + j];
    if (v < best || (v == best && ii < bix)) { best = v; bix = ii; }
  }
  idxout[b] = bix;
  idxf[b] = (float)bix;
  atomicAdd(&counts[bix], 1);
}

__global__ __launch_bounds__(256)
void gather_commit(const int* __restrict__ idx, const float* __restrict__ E,
                   const float* __restrict__ ZE, float* __restrict__ ZQ,
                   float* __restrict__ cpart)
{
  __shared__ float red[4];
  const int b = blockIdx.x * 8 + (threadIdx.x >> 5);
  const int ch = threadIdx.x & 31;
  const int k = idx[b];
  float4 q = *reinterpret_cast<const float4*>(E + (size_t)k * 128 + ch * 4);
  float4 z = *reinterpret_cast<const float4*>(ZE + (size_t)b * 128 + ch * 4);
  *reinterpret_cast<float4*>(ZQ + (size_t)b * 128 + ch * 4) = q;
  float dx = q.x - z.x, dy = q.y - z.y, dz = q.z - z.z, dw = q.w - z.w;
  float s = dx * dx + dy * dy + dz * dz + dw * dw;
  #pragma unroll
  for (int m = 32; m; m >>= 1) s += __shfl_down(s, m);
  const int lane = threadIdx.x & 63, wv = threadIdx.x >> 6;
  if (lane == 0) red[wv] = s;
  __syncthreads();
  if (threadIdx.x == 0) cpart[blockIdx.x] = red[0] + red[1] + red[2] + red[3];
}

__global__ void e2_kernel(const float* __restrict__ E, float* __restrict__ e2)
{
  const int k = blockIdx.x * 256 + threadIdx.x;
  if (k >= KCODES) return;
  float s = 0.f;
  #pragma unroll 4
  for (int d = 0; d < 128; ++d) { float v = E[(size_t)k * 128 + d]; s += v * v; }
  e2[k] = s;
}

__global__ void zero_counts(int* counts)
{
  const int i = blockIdx.x * 256 + threadIdx.x;
  if (i < KCODES) counts[i] = 0;
}

__global__ void gelu_ew(float* __restrict__ p, int n)
{
  const int i = blockIdx.x * 256 + threadIdx.x;
  if (i < n) { float v = p[i]; p[i] = 0.5f * v * (1.f + erff(v * 0.70710678118654752f)); }
}

__global__ void gemm_n2(const float* __restrict__ T, const float* __restrict__ W6,
                        const float* __restrict__ b6, float* __restrict__ V, int M)
{
  const int r = blockIdx.x * 256 + threadIdx.x;
  if (r >= M) return;
  float a0 = b6[0], a1 = b6[1];
  #pragma unroll 4
  for (int d = 0; d < 128; ++d) {
    float t = T[(size_t)r * 128 + d];
    a0 = fmaf(t, W6[d * 2 + 0], a0);
    a1 = fmaf(t, W6[d * 2 + 1], a1);
  }
  V[r * 2 + 0] = a0; V[r * 2 + 1] = a1;
}

__global__ void vel_gather(const int* __restrict__ idx, const float* __restrict__ V,
                           float* __restrict__ out)
{
  const int b = blockIdx.x * 256 + threadIdx.x;
  if (b >= B_ROWS) return;
  const int k = idx[b];
  out[b * 2 + 0] = V[k * 2 + 0];
  out[b * 2 + 1] = V[k * 2 + 1];
}

__global__ __launch_bounds__(256)
void stats_kernel(const float* __restrict__ cpart, const int* __restrict__ counts,
                  float* __restrict__ outs)
{
  __shared__ float sh[256];
  __shared__ float sh2[256];
  __shared__ int shi[256];
  const int t = threadIdx.x;
  float cs = 0.f;
  for (int i = t; i < 4096; i += 256) cs += cpart[i];
  float h = 0.f; int act = 0;
  for (int k = t; k < KCODES; k += 256) {
    float avg = counts[k] * (1.0f / 32768.0f);
    h += avg * logf(avg + 1e-10f);
    act += (avg > 0.001f) ? 1 : 0;
  }
  sh[t] = cs; sh2[t] = h; shi[t] = act;
  __syncthreads();
  for (int s = 128; s; s >>= 1) {
    if (t < s) { sh[t] += sh[t + s]; sh2[t] += sh2[t + s]; shi[t] += shi[t + s]; }
    __syncthreads();
  }
  if (t == 0) {
    outs[0] = 0.25f * sh[0] / (32768.0f * 128.0f);
    outs[1] = expf(-sh2[0]);
    outs[2] = (float)shi[0];
  }
}

extern "C" void kernel_launch(void* const* d_in, const int* in_sizes, int n_in,
                              void* d_out, int out_size, void* d_ws, size_t ws_size,
                              hipStream_t stream)
{
  const float* x   = (const float*)d_in[0];
  const float* W1  = (const float*)d_in[1];
  const float* b1  = (const float*)d_in[2];
  const float* g1  = (const float*)d_in[3];
  const float* be1 = (const float*)d_in[4];
  const float* W2  = (const float*)d_in[5];
  const float* b2  = (const float*)d_in[6];
  const float* g2  = (const float*)d_in[7];
  const float* be2 = (const float*)d_in[8];
  const float* W3  = (const float*)d_in[9];
  const float* b3  = (const float*)d_in[10];
  const float* emb = (const float*)d_in[11];
  const float* W4  = (const float*)d_in[12];
  const float* b4  = (const float*)d_in[13];
  const float* g3  = (const float*)d_in[14];
  const float* be3 = (const float*)d_in[15];
  const float* W5  = (const float*)d_in[16];
  const float* b5  = (const float*)d_in[17];
  const float* W6  = (const float*)d_in[18];
  const float* b6  = (const float*)d_in[19];

  float* out = (float*)d_out;
  float* o_vel  = out;                                   // [B,2]
  float* o_ze   = out + 65536;                           // [B,128]
  float* o_zq   = out + 65536 + B_ROWS * 128;            // [B,128]
  float* o_idx  = out + 65536 + 2 * B_ROWS * 128;        // [B] (as float)
  float* o_scal = o_idx + B_ROWS;                        // 3 scalars

  float* ws = (float*)d_ws;
  float* h1f   = ws;                        // [B,512] f32 -> in-place split halves
  float* pval  = ws;                        // [B,16]
  int*   pidx  = (int*)(ws + 524288);       // [B,16]
  float* t1f   = ws + 1048576;              // [4096,256] f32 -> in-place split
  float* t2    = ws + 2097152;              // [4096,128]
  float* vv    = ws + 2621440;              // [4096,2]
  float* h2f   = ws + 16777216;             // [B,256] f32 -> in-place split
  float* e2    = ws + 25165824;             // [4096]
  int*   ind   = (int*)(ws + 25169920);     // [B]
  int*   cnt   = (int*)(ws + 25202688);     // [4096]
  float* cpart = ws + 25206784;             // [4096]
  _Float16* hb  = (_Float16*)(ws + 25210880);
  _Float16* E1  = hb;                       // 4096*128
  _Float16* E2  = E1 + 524288;
  _Float16* W1a = E2 + 524288;              // [512][1440]
  _Float16* W1b = W1a + 737280;
  _Float16* W2a = W1b + 737280;             // [256][512]
  _Float16* W2b = W2a + 131072;
  _Float16* W3a = W2b + 131072;             // [128][256]
  _Float16* W3b = W3a + 32768;
  _Float16* W4a = W3b + 32768;              // [256][128]
  _Float16* W4b = W4a + 32768;
  _Float16* W5a = W4b + 32768;              // [128][256]
  _Float16* W5b = W5a + 32768;

  // 1. init + weight prep
  zero_counts<<<16, 256, 0, stream>>>(cnt);
  e2_kernel<<<16, 256, 0, stream>>>(emb, e2);
  prep_emb<<<2048, 256, 0, stream>>>(emb, E1, E2);
  prep_wT<<<2880, 256, 0, stream>>>(W1, W1a, W1b, 1420, 512, 9, 511, 1440);
  prep_wT<<<512, 256, 0, stream>>>(W2, W2a, W2b, 512, 256, 8, 255, 512);
  prep_wT<<<128, 256, 0, stream>>>(W3, W3a, W3b, 256, 128, 7, 127, 256);
  prep_wT<<<128, 256, 0, stream>>>(W4, W4a, W4b, 128, 256, 8, 255, 128);
  prep_wT<<<128, 256, 0, stream>>>(W5, W5a, W5b, 256, 128, 7, 127, 256);

  // 2. encoder (grid = nbx * mblocks, XCD-swizzled inside)
  hgemm<true><<<8 * 256, 256, 0, stream>>>(x, nullptr, nullptr, 0,
      W1a, W1b, b1, h1f, B_ROWS, 512, 1420, 1440, 8);
  ln_gelu_split<<<B_ROWS, 256, 0, stream>>>(h1f, g1, be1, 512);
  hgemm<false><<<4 * 256, 256, 0, stream>>>(nullptr,
      (const _Float16*)h1f, (const _Float16*)h1f + 512, 1024,
      W2a, W2b, b2, h2f, B_ROWS, 256, 512, 512, 4);
  ln_gelu_split<<<B_ROWS, 256, 0, stream>>>(h2f, g2, be2, 256);
  hgemm<false><<<2 * 256, 256, 0, stream>>>(nullptr,
      (const _Float16*)h2f, (const _Float16*)h2f + 256, 512,
      W3a, W3b, b3, o_ze, B_ROWS, 128, 256, 256, 2);

  // 3. VQ
  vq_mfma<<<2048, 256, 0, stream>>>(o_ze, E1, E2, e2, pval, pidx);
  vq_reduce<<<128, 256, 0, stream>>>(pval, pidx, ind, o_idx, cnt);
  gather_commit<<<4096, 256, 0, stream>>>(ind, emb, o_ze, o_zq, cpart);

  // 4. decoder on the 4096 distinct codes, then gather
  hgemm<false><<<4 * 32, 256, 0, stream>>>(nullptr, E1, E2, 128,
      W4a, W4b, b4, t1f, KCODES, 256, 128, 128, 4);
  ln_gelu_split<<<KCODES, 256, 0, stream>>>(t1f, g3, be3, 256);
  hgemm<false><<<2 * 32, 256, 0, stream>>>(nullptr,
      (const _Float16*)t1f, (const _Float16*)t1f + 256, 512,
      W5a, W5b, b5, t2, KCODES, 128, 256, 256, 2);
  gelu_ew<<<(KCODES * 128 + 255) / 256, 256, 0, stream>>>(t2, KCODES * 128);
  gemm_n2<<<(KCODES + 255) / 256, 256, 0, stream>>>(t2, W6, b6, vv, KCODES);
  vel_gather<<<128, 256, 0, stream>>>(ind, vv, o_vel);

  // 5. scalars
  stats_kernel<<<1, 256, 0, stream>>>(cpart, cnt, o_scal);
}